// Round 18
// baseline (287.295 us; speedup 1.0000x reference)
//
#include <hip/hip_runtime.h>
#include <hip/hip_bf16.h>

#define B_   8
#define S_   2048
#define DM   1024
#define DH   128
#define BS_  16384
#define SCALE_  0.08838834764831845f
#define SCALE2_ 0.12751744f   // SCALE * log2(e)

typedef unsigned short u16;
typedef unsigned int   u32;
typedef _Float16 half8 __attribute__((ext_vector_type(8)));
typedef __bf16   bf16x8 __attribute__((ext_vector_type(8)));
typedef float    f32x4 __attribute__((ext_vector_type(4)));
typedef u32      u32x4 __attribute__((ext_vector_type(4)));

union H8 { u32x4 v; u32 u[4]; half8 h; bf16x8 b; };

__device__ __forceinline__ float bf2f(u16 u) {
    union { u32 i; float f; } w; w.i = ((u32)u) << 16; return w.f;
}
__device__ __forceinline__ void unpack8(uint4 v, float* f) {
    f[0] = bf2f(v.x & 0xffff); f[1] = bf2f(v.x >> 16);
    f[2] = bf2f(v.y & 0xffff); f[3] = bf2f(v.y >> 16);
    f[4] = bf2f(v.z & 0xffff); f[5] = bf2f(v.z >> 16);
    f[6] = bf2f(v.w & 0xffff); f[7] = bf2f(v.w >> 16);
}
__device__ __forceinline__ float ldE(const void* b, size_t i, int isbf16) {
    return isbf16 ? bf2f(((const u16*)b)[i]) : ((const float*)b)[i];
}
__device__ __forceinline__ void ld8(const void* b, size_t i, int isbf16, float* f) {
    if (isbf16) {
        unpack8(*(const uint4*)((const u16*)b + i), f);
    } else {
        float4 a = *(const float4*)((const float*)b + i);
        float4 c = *(const float4*)((const float*)b + i + 4);
        f[0] = a.x; f[1] = a.y; f[2] = a.z; f[3] = a.w;
        f[4] = c.x; f[5] = c.y; f[6] = c.z; f[7] = c.w;
    }
}
// fp32 -> packed (f16 hi << 16) | f16 lo  (2-term split, ~22 mantissa bits)
__device__ __forceinline__ u32 f2pk(float v) {
    _Float16 h = (_Float16)v;
    _Float16 l = (_Float16)(v - (float)h);
    union { _Float16 f; u16 u; } a, b; a.f = h; b.f = l;
    return ((u32)a.u << 16) | (u32)b.u;
}
// 8 floats -> pair-packed hi/lo frag u32x4
__device__ __forceinline__ void split8(const float* f, u32x4& hi, u32x4& lo) {
    u32 H[8], L[8];
#pragma unroll
    for (int j = 0; j < 8; ++j) {
        _Float16 h = (_Float16)f[j];
        _Float16 l = (_Float16)(f[j] - (float)h);
        union { _Float16 x; u16 u; } a, b; a.x = h; b.x = l;
        H[j] = a.u; L[j] = b.u;
    }
    hi = (u32x4){H[0] | (H[1] << 16), H[2] | (H[3] << 16), H[4] | (H[5] << 16), H[6] | (H[7] << 16)};
    lo = (u32x4){L[0] | (L[1] << 16), L[2] | (L[3] << 16), L[4] | (L[5] << 16), L[6] | (L[7] << 16)};
}
__device__ __forceinline__ u32 permHI(u32 eB, u32 eA) { return __builtin_amdgcn_perm(eB, eA, 0x07060302u); }
__device__ __forceinline__ u16 f2h(float v) { union { _Float16 f; u16 u; } a; a.f = (_Float16)v; return a.u; }
__device__ __forceinline__ float h2f(u16 u) { union { _Float16 f; u16 u; } a; a.u = u; return (float)a.f; }

// ---------------- init: dtype detect + active mask + round counters ----------------
__global__ void init_kernel(const void* x, int* flag, int* active, int* counts) {
    int i = blockIdx.x * 256 + threadIdx.x;
    if (i < BS_) active[i] = 1;
    if (i < 4) counts[i] = (i == 0) ? BS_ : 0;
    if (i == 0) {
        const u16* w = (const u16*)x;
        int sane = 0;
        for (int t = 0; t < 256; ++t) {
            int e = (w[2 * t] >> 7) & 0xFF;
            if (e >= 100 && e <= 135) ++sane;
        }
        *flag = (sane >= 192) ? 1 : 0;   // 1 = bf16, 0 = fp32
    }
}

// ---------------- prepack W into MFMA fragment layout ----------------
// bf16 path: hi slot = raw bf16 pairs (lo unused). fp32 path: f16 hi/lo split.
__global__ __launch_bounds__(256) void prepack_w_kernel(
    const void* __restrict__ wq, const void* __restrict__ wk, const void* __restrict__ wv,
    const int* __restrict__ flag, u32x4* __restrict__ wpk)
{
    const int isb = *flag;
    const int gid = blockIdx.x * 256 + threadIdx.x;
    const int l  = gid & 63;
    const int t  = (gid >> 6) & 7;
    const int ks = (gid >> 9) & 31;
    const int z  = gid >> 14;
    const void* W = (z == 0) ? wq : (z == 1) ? wk : wv;
    const int row = 16 * t + (l & 15);
    const int k0  = ks * 32 + 8 * (l >> 4);
    const size_t base = ((((size_t)z * 32 + ks) * 16) + 2 * t) * 64 + l;
    if (isb) {
        uint4 v = *(const uint4*)((const u16*)W + (size_t)row * DM + k0);
        wpk[base] = (u32x4){v.x, v.y, v.z, v.w};
    } else {
        float f[8];
        ld8(W, (size_t)row * DM + k0, 0, f);
        u32x4 hi, lo;
        split8(f, hi, lo);
        wpk[base]      = hi;
        wpk[base + 64] = lo;
    }
}

// ---------------- MFMA QKV: 64 rows/block, 512 threads (8 waves), BK=64 staged ----------------
// z=0: Q packs. z=1: K MFMA-frags. z=2: V MFMA-frags.
// Wave (rowg = wave>>1, colh = wave&1): 16 rows x 64 cols, acc[4]. Same math as R17.
__global__ __launch_bounds__(512) void qkv_kernel(
    const void* __restrict__ x, const u32x4* __restrict__ wpk,
    const int* __restrict__ flag, u32* __restrict__ qout,
    u32x4* __restrict__ kfrag, u32x4* __restrict__ vfrag)
{
    const int isb = *flag;
    const int z = blockIdx.z;
    // XCD swizzle (bijective on [0,256)): consecutive x-tiles stay on one XCD
    const int bx = blockIdx.x;
    const int m0 = ((bx & 7) * 32 + (bx >> 3)) * 64;
    const int tid = threadIdx.x;
    const int wave = tid >> 6, lane = tid & 63;
    const int qd = lane >> 4, c = lane & 15;
    const int rowg = wave >> 1, colh = wave & 1;

    __shared__ u32x4 WLraw[2][16][64];   // 32 KB; TS overlays after the loop
    // views
    u32x4 (*WLb)[2][8][64] = (u32x4(*)[2][8][64])WLraw;   // bf16: [buf][ksub][t][lane]
    u32x4 (*WLf)[8][2][64] = (u32x4(*)[8][2][64])WLraw;   // fp32: [buf][t][plane][lane]
    u16 (*TS)[136] = (u16(*)[136])WLraw;                  // 17.4 KB overlay

    const u32x4* wz = wpk + (size_t)z * (32 * 16 * 64);
    const size_t arow = (size_t)(m0 + 16 * rowg + c) * DM + 8 * qd;

// bf16 BK=64 stage: iter i covers ks=2i,2i+1; 16 hi slabs, 2 per wave
#define STAGE2(i_, b_)                                                            \
    {                                                                             \
        _Pragma("unroll")                                                         \
        for (int _j = 0; _j < 2; ++_j) {                                          \
            const int _g = wave * 2 + _j, _ksub = _g >> 3, _t = _g & 7;           \
            __builtin_amdgcn_global_load_lds(                                     \
                (const __attribute__((address_space(1))) u32*)(                   \
                    wz + ((size_t)(2 * (i_) + _ksub) * 16 + 2 * _t) * 64 + lane), \
                (__attribute__((address_space(3))) u32*)&WLb[b_][_ksub][_t][0],   \
                16, 0, 0);                                                        \
        }                                                                         \
    }
// fp32 stage (1 K-step): 16 slabs (8 tiles x hi/lo), 2 per wave
#define STAGE_W(ks_, b_)                                                          \
    {                                                                             \
        _Pragma("unroll")                                                         \
        for (int _j = 0; _j < 2; ++_j) {                                          \
            const int _s = wave * 2 + _j;                                         \
            __builtin_amdgcn_global_load_lds(                                     \
                (const __attribute__((address_space(1))) u32*)(                   \
                    wz + ((size_t)(ks_) * 16 + _s) * 64 + lane),                  \
                (__attribute__((address_space(3))) u32*)&WLf[b_][_s >> 1][_s & 1][0], \
                16, 0, 0);                                                        \
        }                                                                         \
    }

    f32x4 acc[4] = {};

    if (isb) {
        const u16* xb = (const u16*)x;
        uint4 A0 = *(const uint4*)(xb + arow);
        uint4 A1 = *(const uint4*)(xb + arow + 32);
        STAGE2(0, 0);
        uint4 A0n = *(const uint4*)(xb + arow + 64);
        uint4 A1n = *(const uint4*)(xb + arow + 96);
        __syncthreads();
        for (int i = 0; i < 16; ++i) {
            const int cb = i & 1;
            if (i + 1 < 16) STAGE2(i + 1, cb ^ 1);
            H8 Ah0; Ah0.v = (u32x4){A0.x, A0.y, A0.z, A0.w};
            H8 Ah1; Ah1.v = (u32x4){A1.x, A1.y, A1.z, A1.w};
#pragma unroll
            for (int tl = 0; tl < 4; ++tl) {
                H8 bh; bh.v = WLb[cb][0][4 * colh + tl][lane];
                acc[tl] = __builtin_amdgcn_mfma_f32_16x16x32_bf16(Ah0.b, bh.b, acc[tl], 0, 0, 0);
            }
#pragma unroll
            for (int tl = 0; tl < 4; ++tl) {
                H8 bh; bh.v = WLb[cb][1][4 * colh + tl][lane];
                acc[tl] = __builtin_amdgcn_mfma_f32_16x16x32_bf16(Ah1.b, bh.b, acc[tl], 0, 0, 0);
            }
            A0 = A0n; A1 = A1n;
            if (i + 2 < 16) {
                A0n = *(const uint4*)(xb + arow + (size_t)(i + 2) * 64);
                A1n = *(const uint4*)(xb + arow + (size_t)(i + 2) * 64 + 32);
            }
            __syncthreads();
        }
    } else {
        float Ar[8], Arn[8];
        ld8(x, arow, 0, Ar);
        STAGE_W(0, 0);
        ld8(x, arow + 32, 0, Arn);
        __syncthreads();
        for (int ks = 0; ks < 32; ++ks) {
            const int cb = ks & 1;
            if (ks + 1 < 32) STAGE_W(ks + 1, cb ^ 1);
            H8 Ah, Al;
            split8(Ar, Ah.v, Al.v);
#pragma unroll
            for (int tl = 0; tl < 4; ++tl) {
                H8 bh, bl;
                bh.v = WLf[cb][4 * colh + tl][0][lane];
                bl.v = WLf[cb][4 * colh + tl][1][lane];
                acc[tl] = __builtin_amdgcn_mfma_f32_16x16x32_f16(Al.h, bh.h, acc[tl], 0, 0, 0);
                acc[tl] = __builtin_amdgcn_mfma_f32_16x16x32_f16(Ah.h, bl.h, acc[tl], 0, 0, 0);
                acc[tl] = __builtin_amdgcn_mfma_f32_16x16x32_f16(Ah.h, bh.h, acc[tl], 0, 0, 0);
            }
#pragma unroll
            for (int j = 0; j < 8; ++j) Ar[j] = Arn[j];
            if (ks + 2 < 32) ld8(x, arow + (size_t)(ks + 2) * 32, 0, Arn);
            __syncthreads();
        }
    }
#undef STAGE2
#undef STAGE_W

    if (z == 0) {
#pragma unroll
        for (int r = 0; r < 4; ++r) {
            const int row = m0 + 16 * rowg + 4 * qd + r;
            u32* op = qout + (size_t)row * DH + 64 * colh + c;
#pragma unroll
            for (int tl = 0; tl < 4; ++tl) op[tl * 16] = f2pk(acc[tl][r]);
        }
    } else {
        // stage [key(local)][dh] f16 tile (overlays WL; loop's final barrier protects)
#pragma unroll
        for (int tl = 0; tl < 4; ++tl)
#pragma unroll
            for (int r = 0; r < 4; ++r)
                TS[16 * rowg + 4 * qd + r][16 * (4 * colh + tl) + c] = f2h(acc[tl][r]);
        __syncthreads();
        if (z == 1) {
            // kfrag[kt16][ks][lane] = K[kt16*16 + (lane&15)][ks*32 + 8*(lane>>4) + j]
#pragma unroll
            for (int i = 0; i < 2; ++i) {
                const int f = tid + 512 * i;          // 0..1023
                const int lf = f & 63, ks = (f >> 6) & 3, sub = f >> 8;
                const int key = sub * 16 + (lf & 15);
                const int d0  = ks * 32 + 8 * (lf >> 4);
                u32 w[4];
#pragma unroll
                for (int q = 0; q < 4; ++q)
                    w[q] = (u32)TS[key][d0 + 2 * q] | ((u32)TS[key][d0 + 2 * q + 1] << 16);
                kfrag[((size_t)(m0 / 16 + sub) * 4 + ks) * 64 + lf] = (u32x4){w[0], w[1], w[2], w[3]};
            }
        } else {
            // vfrag[kt32][t][lane] = V[kt32*32 + 8*(lane>>4) + j][16t + (lane&15)]
#pragma unroll
            for (int i = 0; i < 2; ++i) {
                const int f = tid + 512 * i;          // 0..1023
                const int lf = f & 63, t = (f >> 6) & 7, sub = f >> 9;
                const int kb2 = sub * 32 + 8 * (lf >> 4);
                const int dh  = 16 * t + (lf & 15);
                u32 w[4];
#pragma unroll
                for (int q = 0; q < 4; ++q)
                    w[q] = (u32)TS[kb2 + 2 * q][dh] | ((u32)TS[kb2 + 2 * q + 1][dh] << 16);
                vfrag[((size_t)(m0 / 32 + sub) * 8 + t) * 64 + lf] = (u32x4){w[0], w[1], w[2], w[3]};
            }
        }
    }
}

// ---------------- attention core: barrier-free, frags from global (L2-hot) ----------------
// PB stride 40 u16 (80 B): rows 16B-aligned -> P re-read is one ds_read_b128, conflict-free.
template <bool WRITE_PARTIAL>
__device__ __forceinline__ void attn_body(
    const u32* qp, const u32x4* __restrict__ kfrag, const u32x4* __restrict__ vfrag,
    u16* outO, u16* outL, float* cur,
    int b, int q0, int kt0, int kt1, int part)
{
    const int tid = threadIdx.x;
    const int wave = tid >> 6, lane = tid & 63;
    const int qd = lane >> 4, c = lane & 15;

    __shared__ __align__(16) u16 PB[4][640];   // per-wave P, stride 40 (wave-private)

    H8 Qh[4];
    {
        const u32* qr = qp + ((size_t)b * S_ + q0 + wave * 16 + c) * DH;
#pragma unroll
        for (int ks = 0; ks < 4; ++ks) {
            uint4 e0 = *(const uint4*)(qr + ks * 32 + qd * 8);
            uint4 e1 = *(const uint4*)(qr + ks * 32 + qd * 8 + 4);
            Qh[ks].u[0] = permHI(e0.y, e0.x); Qh[ks].u[1] = permHI(e0.w, e0.z);
            Qh[ks].u[2] = permHI(e1.y, e1.x); Qh[ks].u[3] = permHI(e1.w, e1.z);
        }
    }

    f32x4 O[8] = {};
    float lsum[4] = {};

    const u32x4* kb0 = kfrag + (size_t)b * 128 * 256;   // kt16 stride = 4*64
    const u32x4* vb0 = vfrag + (size_t)b * 64 * 512;    // kt32 stride = 8*64

    for (int kt = kt0; kt < kt1; ++kt) {
        const u32x4* kf = kb0 + (size_t)kt * 512;       // two kt16 blocks
        const u32x4* vf = vb0 + (size_t)kt * 512;

        f32x4 S0 = {}, S1 = {};
        __builtin_amdgcn_s_setprio(1);
#pragma unroll
        for (int ks = 0; ks < 4; ++ks) {
            H8 kh;
            kh.v = kf[ks * 64 + lane];
            S0 = __builtin_amdgcn_mfma_f32_16x16x32_f16(Qh[ks].h, kh.h, S0, 0, 0, 0);
            kh.v = kf[256 + ks * 64 + lane];
            S1 = __builtin_amdgcn_mfma_f32_16x16x32_f16(Qh[ks].h, kh.h, S1, 0, 0, 0);
        }
        __builtin_amdgcn_s_setprio(0);

        u16* pw = PB[wave];
#pragma unroll
        for (int r = 0; r < 4; ++r) {
            float e0 = exp2f(fmaf(S0[r], SCALE2_, -4.0f));
            float e1 = exp2f(fmaf(S1[r], SCALE2_, -4.0f));
            lsum[r] += e0 + e1;
            pw[(4 * qd + r) * 40 + c]      = f2h(e0);
            pw[(4 * qd + r) * 40 + 16 + c] = f2h(e1);
        }

        uint4 ev = *(const uint4*)&pw[c * 40 + 8 * qd];   // one b128: P row c, keys 8qd..8qd+7
        H8 Ph;
        Ph.u[0] = ev.x; Ph.u[1] = ev.y; Ph.u[2] = ev.z; Ph.u[3] = ev.w;

        __builtin_amdgcn_s_setprio(1);
#pragma unroll
        for (int t = 0; t < 8; ++t) {
            H8 vh;
            vh.v = vf[t * 64 + lane];
            O[t] = __builtin_amdgcn_mfma_f32_16x16x32_f16(Ph.h, vh.h, O[t], 0, 0, 0);
        }
        __builtin_amdgcn_s_setprio(0);
    }

    if (WRITE_PARTIAL) {
        float lred[4];
#pragma unroll
        for (int r = 0; r < 4; ++r) {
            float l = lsum[r];
            l += __shfl_xor(l, 1); l += __shfl_xor(l, 2);
            l += __shfl_xor(l, 4); l += __shfl_xor(l, 8);
            lred[r] = l;
        }
        const size_t rb = (size_t)b * S_ + q0 + wave * 16 + 4 * qd;
        u16* Op = outO + (size_t)part * ((size_t)BS_ * DH);
#pragma unroll
        for (int t = 0; t < 8; ++t)
#pragma unroll
            for (int r = 0; r < 4; ++r)
                Op[(rb + r) * DH + t * 16 + c] = f2h(O[t][r]);
        if (c == 0) {
            u16* lp = outL + (size_t)part * BS_;
#pragma unroll
            for (int r = 0; r < 4; ++r) lp[rb + r] = f2h(lred[r]);
        }
    } else {
        float linv[4];
#pragma unroll
        for (int r = 0; r < 4; ++r) {
            float l = lsum[r];
            l += __shfl_xor(l, 1); l += __shfl_xor(l, 2);
            l += __shfl_xor(l, 4); l += __shfl_xor(l, 8);
            linv[r] = 1.0f / l;
        }
        const size_t rb = (size_t)b * S_ + q0 + wave * 16 + 4 * qd;
#pragma unroll
        for (int t = 0; t < 8; ++t)
#pragma unroll
            for (int r = 0; r < 4; ++r)
                cur[(rb + r) * DH + t * 16 + c] = O[t][r] * linv[r];
    }
}

// single-pass fallback: grid (32, 8). XCD swizzle: batch = rid&7 (bijective).
__global__ __launch_bounds__(256) void attn_kernel(
    const u32* qp, const u32x4* __restrict__ kfrag, const u32x4* __restrict__ vfrag, float* cur)
{
    const int rid = blockIdx.x + 32 * blockIdx.y;
    attn_body<false>(qp, kfrag, vfrag, nullptr, nullptr, cur,
                     rid & 7, ((rid >> 3) & 31) * 64, 0, S_ / 32, 0);
}

// split-KV x4: grid (32, 8, 4) = 1024 blocks. batch = rid&7 per XCD.
__global__ __launch_bounds__(256) void attn_split_kernel(
    const u32* qp, const u32x4* __restrict__ kfrag, const u32x4* __restrict__ vfrag,
    u16* __restrict__ Opart, u16* __restrict__ lpart)
{
    const int rid = blockIdx.x + 32 * (blockIdx.y + 8 * blockIdx.z);
    const int b    = rid & 7;
    const int qx   = (rid >> 3) & 31;
    const int part = rid >> 8;
    const int quart = S_ / 128;   // 16 tiles per part
    attn_body<true>(qp, kfrag, vfrag, Opart, lpart, nullptr,
                    b, qx * 64, part * quart, (part + 1) * quart, part);
}

// ---------------- prepack round weights (straight repack, no algebra) ----------------
// mats: 0=tw, 1=w1[:,0:128], 2=w1[:,128:256], 3=w1[:,256:384], 4=w2
__global__ __launch_bounds__(256) void prepack_rw_kernel(
    const void* __restrict__ tw, const void* __restrict__ w1, const void* __restrict__ w2,
    const int* __restrict__ flag, u32x4* __restrict__ pk)
{
    const int isb = *flag;
    const int gid = blockIdx.x * 256 + threadIdx.x;   // 10240 total
    const int l = gid & 63, t = (gid >> 6) & 7, ks = (gid >> 9) & 3, mat = gid >> 11;
    const int row = 16 * t + (l & 15);
    const int k0  = ks * 32 + 8 * (l >> 4);
    float f[8];
    if (mat == 0)      ld8(tw, (size_t)row * DH + k0, isb, f);
    else if (mat <= 3) ld8(w1, (size_t)row * 384 + (mat - 1) * 128 + k0, isb, f);
    else               ld8(w2, (size_t)row * DH + k0, isb, f);
    u32x4 hi, lo;
    split8(f, hi, lo);
    const size_t base = (((size_t)mat * 4 + ks) * 16 + 2 * t) * 64 + l;
    pk[base] = hi; pk[base + 64] = lo;
}

// pre-split A fragments
struct Afrag { H8 h[4], l[4]; };
__device__ __forceinline__ void splitA(const float (&A)[4][8], Afrag& F) {
#pragma unroll
    for (int ks = 0; ks < 4; ++ks) split8(A[ks], F.h[ks].v, F.l[ks].v);
}

// ---------------- round 0: fused combine + dialectic round, 16 tokens/block, grid 1024 ----------
// Builds combined cur0 in LDS (CS, f32, bit-identical to old combine_kernel output),
// runs round-0 math (all tokens active, am=1), caches t0 to T0 for rounds 1-2.
__global__ __launch_bounds__(256) void round0_kernel(
    const float* __restrict__ cur0g,
    const u16* __restrict__ Opart, const u16* __restrict__ lpart,
    const u32x4* __restrict__ pk, u16* __restrict__ T0,
    const void* __restrict__ tb, const void* __restrict__ ab,
    const void* __restrict__ b1, const void* __restrict__ b2,
    const void* __restrict__ gw, const void* __restrict__ gb,
    const int* __restrict__ flag, int* active, int* counts,
    float* cur_out, int combine)
{
    const int isb = *flag;
    const int tok0 = blockIdx.x * 16;
    const int tid = threadIdx.x;
    const int wave = tid >> 6, lane = tid & 63;
    const int qd = lane >> 4, c = lane & 15;

    __shared__ u32x4 WB[2][2][8][64];   // 32 KB: [buf][kl(or plane)][t][lane]
    __shared__ u16 TS[16][132];         // t0 -> h -> synth (f16)
    __shared__ float CS[16][128];       // combined cur0 rows (f32, 8 KB)
    __shared__ float tbS[128], abS[128], b1S[128], b2S[128], gwS[256];
    __shared__ int blkcnt;

    auto stageBh = [&](int mat, int h) {
#pragma unroll
        for (int j = 0; j < 4; ++j) {
            const int g = wave * 4 + j, kl = g >> 3, t = g & 7;
            __builtin_amdgcn_global_load_lds(
                (const __attribute__((address_space(1))) u32*)(
                    pk + (((size_t)mat * 4 + 2 * h + kl) * 16 + 2 * t) * 64 + lane),
                (__attribute__((address_space(3))) u32*)&WB[h][kl][t][0],
                16, 0, 0);
        }
    };
    auto gemmBh = [&](const Afrag& F, int h, f32x4 (&acc)[2]) {
#pragma unroll
        for (int kl = 0; kl < 2; ++kl) {
            const int ks = 2 * h + kl;
#pragma unroll
            for (int tl = 0; tl < 2; ++tl) {
                H8 bh; bh.v = WB[h][kl][2 * wave + tl][lane];
                acc[tl] = __builtin_amdgcn_mfma_f32_16x16x32_f16(F.l[ks].h, bh.h, acc[tl], 0, 0, 0);
                acc[tl] = __builtin_amdgcn_mfma_f32_16x16x32_f16(F.h[ks].h, bh.h, acc[tl], 0, 0, 0);
            }
        }
    };
    auto stageFq = [&](int mat, int q, int buf) {
#pragma unroll
        for (int j = 0; j < 4; ++j) {
            const int g = wave * 4 + j, p = g & 1, t = g >> 1;
            __builtin_amdgcn_global_load_lds(
                (const __attribute__((address_space(1))) u32*)(
                    pk + (((size_t)mat * 4 + q) * 16 + 2 * t + p) * 64 + lane),
                (__attribute__((address_space(3))) u32*)&WB[buf][p][t][0],
                16, 0, 0);
        }
    };
    auto gemmFq = [&](const Afrag& F, int q, int buf, f32x4 (&acc)[2]) {
#pragma unroll
        for (int tl = 0; tl < 2; ++tl) {
            H8 bh, bl;
            bh.v = WB[buf][0][2 * wave + tl][lane];
            bl.v = WB[buf][1][2 * wave + tl][lane];
            acc[tl] = __builtin_amdgcn_mfma_f32_16x16x32_f16(F.l[q].h, bh.h, acc[tl], 0, 0, 0);
            acc[tl] = __builtin_amdgcn_mfma_f32_16x16x32_f16(F.h[q].h, bl.h, acc[tl], 0, 0, 0);
            acc[tl] = __builtin_amdgcn_mfma_f32_16x16x32_f16(F.h[q].h, bh.h, acc[tl], 0, 0, 0);
        }
    };
    auto GEMMF = [&](int mat, const Afrag& F, f32x4 (&acc)[2]) {
        for (int q = 0; q < 4; ++q) {
            stageFq(mat, q, q & 1);
            __syncthreads();
            gemmFq(F, q, q & 1, acc);
            __syncthreads();
        }
    };

    const int hr = 4 * qd;
    const int rowl = c;

    auto writeTS = [&](const f32x4 (&acc)[2], const float* bias, bool relu) {
#pragma unroll
        for (int tl = 0; tl < 2; ++tl)
#pragma unroll
            for (int rr = 0; rr < 4; ++rr) {
                const int col = 16 * (2 * wave + tl) + c;
                float v = acc[tl][rr] + (bias ? bias[col] : 0.0f);
                TS[hr + rr][col] = f2h(relu ? fmaxf(v, 0.0f) : v);
            }
    };
    auto buildA1 = [&](Afrag& F) {
        float Ac[4][8];
#pragma unroll
        for (int ks = 0; ks < 4; ++ks)
#pragma unroll
            for (int j = 0; j < 8; ++j)
                Ac[ks][j] = CS[rowl][ks * 32 + 8 * qd + j];
        splitA(Ac, F);
    };
    auto buildAt = [&](Afrag& F) {
        float Ac[4][8];
#pragma unroll
        for (int ks = 0; ks < 4; ++ks)
#pragma unroll
            for (int j = 0; j < 8; ++j) {
                const int k = ks * 32 + 8 * qd + j;
                Ac[ks][j] = h2f(TS[rowl][k]) + tbS[k];
            }
        splitA(Ac, F);
    };
    auto buildAa = [&](Afrag& F) {
        float Ac[4][8];
#pragma unroll
        for (int ks = 0; ks < 4; ++ks)
#pragma unroll
            for (int j = 0; j < 8; ++j) {
                const int k = ks * 32 + 8 * qd + j;
                Ac[ks][j] = abS[k] - h2f(TS[rowl][k]);
            }
        splitA(Ac, F);
    };
    auto buildAh = [&](Afrag& F) {
        float Ac[4][8];
#pragma unroll
        for (int ks = 0; ks < 4; ++ks)
#pragma unroll
            for (int j = 0; j < 8; ++j)
                Ac[ks][j] = h2f(TS[rowl][ks * 32 + 8 * qd + j]);
        splitA(Ac, F);
    };

    // ---- constants + combined cur0 into CS (8 elems/thread) ----
    if (tid < 128) {
        tbS[tid] = ldE(tb, tid, isb); abS[tid] = ldE(ab, tid, isb);
        b1S[tid] = ldE(b1, tid, isb); b2S[tid] = ldE(b2, tid, isb);
    }
    gwS[tid] = ldE(gw, tid, isb);
    if (tid == 0) blkcnt = 0;
    const float gbf = ldE(gb, 0, isb);
    {
        const int row = tid >> 4, d0 = (tid & 15) * 8;
        float a8[8];
        if (combine) {
            const size_t grow = (size_t)(tok0 + row);
            const float lt = h2f(lpart[grow]) + h2f(lpart[BS_ + grow])
                           + h2f(lpart[2 * BS_ + grow]) + h2f(lpart[3 * BS_ + grow]);
            const float linv = 1.0f / lt;
            float acc[8] = {};
            const size_t N1 = (size_t)BS_ * DH;
#pragma unroll
            for (int p = 0; p < 4; ++p) {
                const u16* op = Opart + (size_t)p * N1 + grow * DH + d0;
                uint4 v0 = *(const uint4*)op;
                const u32 w[4] = {v0.x, v0.y, v0.z, v0.w};
#pragma unroll
                for (int j = 0; j < 4; ++j) {
                    acc[2 * j]     += h2f((u16)(w[j] & 0xffff));
                    acc[2 * j + 1] += h2f((u16)(w[j] >> 16));
                }
            }
#pragma unroll
            for (int e = 0; e < 8; ++e) a8[e] = acc[e] * linv;
        } else {
            const float* cr = cur0g + (size_t)(tok0 + row) * DH + d0;
            float4 v0 = *(const float4*)cr;
            float4 v1 = *(const float4*)(cr + 4);
            a8[0] = v0.x; a8[1] = v0.y; a8[2] = v0.z; a8[3] = v0.w;
            a8[4] = v1.x; a8[5] = v1.y; a8[6] = v1.z; a8[7] = v1.w;
        }
#pragma unroll
        for (int e = 0; e < 8; ++e) CS[row][d0 + e] = a8[e];
    }

    if (isb) {
        stageBh(0, 0);
        __syncthreads();                 // WB0(tw.h0) + CS + consts
        Afrag FA; buildA1(FA);
        stageBh(0, 1);
        f32x4 accT[2] = {};
        gemmBh(FA, 0, accT);
        __syncthreads();                 // WB1(tw.h1)
        stageBh(1, 0);
        gemmBh(FA, 1, accT);
        writeTS(accT, nullptr, false);   // t0
        __syncthreads();                 // WB0(w1a.h0) + TS(t0)
        for (int i = tid; i < 16 * 64; i += 256) {
            const int row = i >> 6, c2 = (i & 63) * 2;
            *(u32*)&T0[(size_t)(tok0 + row) * DH + c2] = *(const u32*)&TS[row][c2];
        }
        f32x4 acc1[2] = {};
        {   // at @ w1a
            Afrag FC; buildAt(FC);
            stageBh(1, 1);
            gemmBh(FC, 0, acc1);
            __syncthreads();             // WB1(w1a.h1)
            stageBh(2, 0);
            gemmBh(FC, 1, acc1);
            __syncthreads();             // WB0(w1b.h0)
        }
        {   // aa @ w1b
            Afrag FC; buildAa(FC);
            stageBh(2, 1);
            gemmBh(FC, 0, acc1);
            __syncthreads();             // WB1(w1b.h1)
            stageBh(3, 0);
            gemmBh(FC, 1, acc1);
            __syncthreads();             // WB0(w1c.h0)
        }
        {   // ac @ w1c (A = CS rows, am = 1)
            Afrag FC; buildA1(FC);
            stageBh(3, 1);
            gemmBh(FC, 0, acc1);
            __syncthreads();             // WB1(w1c.h1)
            stageBh(4, 0);
            gemmBh(FC, 1, acc1);
        }
        writeTS(acc1, b1S, true);        // h (t0 readers done >=2 barriers ago)
        __syncthreads();                 // WB0(w2.h0) + TS(h)
        {   // h @ w2
            Afrag FC; buildAh(FC);
            stageBh(4, 1);
            f32x4 acc2[2] = {};
            gemmBh(FC, 0, acc2);
            __syncthreads();             // WB1(w2.h1); separates h reads from synth write
            gemmBh(FC, 1, acc2);
            writeTS(acc2, b2S, false);   // synth
        }
        __syncthreads();                 // synth visible
    } else {
        __syncthreads();                 // CS + consts
        Afrag FA; buildA1(FA);
        f32x4 accT[2] = {};
        GEMMF(0, FA, accT);
        writeTS(accT, nullptr, false);
        __syncthreads();
        for (int i = tid; i < 16 * 64; i += 256) {
            const int row = i >> 6, c2 = (i & 63) * 2;
            *(u32*)&T0[(size_t)(tok0 + row) * DH + c2] = *(const u32*)&TS[row][c2];
        }
        f32x4 acc1[2] = {};
        { Afrag FC; buildAt(FC); GEMMF(1, FC, acc1); }
        { Afrag FC; buildAa(FC); GEMMF(2, FC, acc1); }
        { Afrag FC; buildA1(FC); GEMMF(3, FC, acc1); }
        writeTS(acc1, b1S, true);
        __syncthreads();
        {
            Afrag FC; buildAh(FC);
            f32x4 acc2[2] = {};
            GEMMF(4, FC, acc2);
            writeTS(acc2, b2S, false);
        }
        __syncthreads();
    }

    // ---- gate, update, norm, active (am = 1): 16 threads/token, 8 elems each ----
    const int tok = tid >> 4, d0g = (tid & 15) * 8;
    float cv[8];
#pragma unroll
    for (int e = 0; e < 8; ++e) cv[e] = CS[tok][d0g + e];
    float srow[8];
#pragma unroll
    for (int e = 0; e < 8; ++e) srow[e] = h2f(TS[tok][d0g + e]);
    float gp = 0.0f;
#pragma unroll
    for (int e = 0; e < 8; ++e)
        gp += cv[e] * gwS[d0g + e] + srow[e] * gwS[128 + d0g + e];
    gp += __shfl_xor(gp, 1, 16);
    gp += __shfl_xor(gp, 2, 16);
    gp += __shfl_xor(gp, 4, 16);
    gp += __shfl_xor(gp, 8, 16);
    const float gate = 1.0f / (1.0f + __expf(-(gp + gbf)));
    float ss = 0.0f; float up[8];
#pragma unroll
    for (int e = 0; e < 8; ++e) {
        float u = gate * (srow[e] - cv[e]) * 0.1f;
        up[e] = u; ss += u * u;
    }
    ss += __shfl_xor(ss, 1, 16);
    ss += __shfl_xor(ss, 2, 16);
    ss += __shfl_xor(ss, 4, 16);
    ss += __shfl_xor(ss, 8, 16);
    const bool stable = sqrtf(ss) < 0.1f;

    float* op = cur_out + (size_t)(tok0 + tok) * DH + d0g;
    *(float4*)op       = make_float4(cv[0] + up[0], cv[1] + up[1], cv[2] + up[2], cv[3] + up[3]);
    *(float4*)(op + 4) = make_float4(cv[4] + up[4], cv[5] + up[5], cv[6] + up[6], cv[7] + up[7]);
    const int newact = stable ? 0 : 1;
    if ((tid & 15) == 0) {
        active[tok0 + tok] = newact;
        if (newact) atomicAdd(&blkcnt, 1);
    }
    __syncthreads();
    if (tid == 0 && blkcnt > 0) atomicAdd(&counts[1], blkcnt);
}

// ---------------- rounds 1,2: 32 tokens/block, grid 512, dbuf stage (R15 form) ----------------
__global__ __launch_bounds__(256) void round_kernel(
    const float* curr,
    const u32x4* __restrict__ pk, const u16* __restrict__ T0,
    const void* __restrict__ tb, const void* __restrict__ ab,
    const void* __restrict__ b1, const void* __restrict__ b2,
    const void* __restrict__ gw, const void* __restrict__ gb,
    const int* __restrict__ flag, int* active, int* counts, int r,
    float* cur_out, void* dout)
{
    const int isb = *flag;
    const int tok0 = blockIdx.x * 32;
    const int tid = threadIdx.x;
    const bool last = (dout != nullptr);

    if (counts[r] <= 0) {
        if (last) {
            for (int e = tid; e < 32 * DH; e += 256) {
                size_t idx = (size_t)tok0 * DH + e;
                float v = curr[idx];
                if (isb) ((__hip_bfloat16*)dout)[idx] = __float2bfloat16(v);
                else     ((float*)dout)[idx] = v;
            }
        }
        return;
    }

    const int wave = tid >> 6, lane = tid & 63;
    const int qd = lane >> 4, c = lane & 15;
    const int rowg = wave >> 1, colh = wave & 1;

    __shared__ u32x4 WB[2][4][8][64];   // 64 KB double-buffered weight stage
    __shared__ u16 TS[32][132];         // t0 -> h -> synth (f16, 8.4 KB)
    __shared__ float actS[32], tbS[128], abS[128], b1S[128], b2S[128], gwS[256];
    __shared__ int blkcnt;

    auto stageB = [&](int mat, int buf) {
#pragma unroll
        for (int j = 0; j < 8; ++j) {
            const int g = wave * 8 + j, ks = g >> 3, t = g & 7;
            __builtin_amdgcn_global_load_lds(
                (const __attribute__((address_space(1))) u32*)(
                    pk + (((size_t)mat * 4 + ks) * 16 + 2 * t) * 64 + lane),
                (__attribute__((address_space(3))) u32*)&WB[buf][ks][t][0],
                16, 0, 0);
        }
    };
    auto stageF = [&](int mat, int h, int buf) {
#pragma unroll
        for (int j = 0; j < 8; ++j) {
            const int g = wave * 8 + j, kl = g >> 4, p = (g >> 3) & 1, t = g & 7;
            __builtin_amdgcn_global_load_lds(
                (const __attribute__((address_space(1))) u32*)(
                    pk + (((size_t)mat * 4 + 2 * h + kl) * 16 + 2 * t + p) * 64 + lane),
                (__attribute__((address_space(3))) u32*)&WB[buf][kl * 2 + p][t][0],
                16, 0, 0);
        }
    };
    auto gemmB = [&](const Afrag& F, int buf, f32x4 (&acc)[4]) {
#pragma unroll
        for (int ks = 0; ks < 4; ++ks)
#pragma unroll
            for (int tl = 0; tl < 4; ++tl) {
                H8 bh; bh.v = WB[buf][ks][4 * colh + tl][lane];
                acc[tl] = __builtin_amdgcn_mfma_f32_16x16x32_f16(F.l[ks].h, bh.h, acc[tl], 0, 0, 0);
                acc[tl] = __builtin_amdgcn_mfma_f32_16x16x32_f16(F.h[ks].h, bh.h, acc[tl], 0, 0, 0);
            }
    };
    auto gemmFh = [&](const Afrag& F, int h, int buf, f32x4 (&acc)[4]) {
#pragma unroll
        for (int kl = 0; kl < 2; ++kl) {
            const int ks = 2 * h + kl;
#pragma unroll
            for (int tl = 0; tl < 4; ++tl) {
                H8 bh, bl;
                bh.v = WB[buf][kl * 2][4 * colh + tl][lane];
                bl.v = WB[buf][kl * 2 + 1][4 * colh + tl][lane];
                acc[tl] = __builtin_amdgcn_mfma_f32_16x16x32_f16(F.l[ks].h, bh.h, acc[tl], 0, 0, 0);
                acc[tl] = __builtin_amdgcn_mfma_f32_16x16x32_f16(F.h[ks].h, bl.h, acc[tl], 0, 0, 0);
                acc[tl] = __builtin_amdgcn_mfma_f32_16x16x32_f16(F.h[ks].h, bh.h, acc[tl], 0, 0, 0);
            }
        }
    };
    auto STAGE = [&](int mat, int buf) { if (isb) stageB(mat, buf); else stageF(mat, 0, buf); };
    auto GEMM = [&](int mat, const Afrag& F, int buf, f32x4 (&acc)[4]) {
        if (isb) {
            gemmB(F, buf, acc);
        } else {
            gemmFh(F, 0, buf, acc);
            __syncthreads();
            stageF(mat, 1, buf);
            __syncthreads();
            gemmFh(F, 1, buf, acc);
        }
    };

    STAGE(1, 1);   // w1a (t0 comes from cache)
    if (tid < 32) actS[tid] = active[tok0 + tid] ? 1.0f : 0.0f;
    if (tid < 128) {
        tbS[tid] = ldE(tb, tid, isb); abS[tid] = ldE(ab, tid, isb);
        b1S[tid] = ldE(b1, tid, isb); b2S[tid] = ldE(b2, tid, isb);
    }
    gwS[tid] = ldE(gw, tid, isb);
    if (tid == 0) blkcnt = 0;
    const float gbf = ldE(gb, 0, isb);

    const int rowl = 16 * rowg + c;
    const int hr   = 16 * rowg + 4 * qd;

    // load cached t0 into TS (coalesced u32 copy: 32 rows x 64 u32)
    for (int i = tid; i < 32 * 64; i += 256) {
        const int row = i >> 6, c2 = (i & 63) * 2;
        *(u32*)&TS[row][c2] = *(const u32*)&T0[(size_t)(tok0 + row) * DH + c2];
    }
    __syncthreads();                     // buf1 ready, TS(t0) + consts visible

    STAGE(2, 0);                         // w1b
    f32x4 acc1[4] = {};
    const float am_r = actS[rowl];
    {
        float Ac[4][8];
#pragma unroll
        for (int ks = 0; ks < 4; ++ks)
#pragma unroll
            for (int j = 0; j < 8; ++j) {
                const int k = ks * 32 + 8 * qd + j;
                Ac[ks][j] = (h2f(TS[rowl][k]) + tbS[k]) * am_r;   // at
            }
        Afrag FC; splitA(Ac, FC);
        GEMM(1, FC, 1, acc1);
    }
    __syncthreads();                     // buf0 ready, buf1 free

    STAGE(3, 1);                         // w1c
    {
        float Ac[4][8];
#pragma unroll
        for (int ks = 0; ks < 4; ++ks)
#pragma unroll
            for (int j = 0; j < 8; ++j) {
                const int k = ks * 32 + 8 * qd + j;
                Ac[ks][j] = (abS[k] - h2f(TS[rowl][k])) * am_r;   // aa
            }
        Afrag FC; splitA(Ac, FC);
        GEMM(2, FC, 0, acc1);
    }
    __syncthreads();                     // buf1 ready; all TS(t0) reads complete

    STAGE(4, 0);                         // w2
    {
        float Ac[4][8];
        const float* cr = curr + (size_t)(tok0 + rowl) * DH;
#pragma unroll
        for (int ks = 0; ks < 4; ++ks) {
            float4 a0 = *(const float4*)(cr + ks * 32 + 8 * qd);
            float4 a1 = *(const float4*)(cr + ks * 32 + 8 * qd + 4);
            Ac[ks][0] = a0.x * am_r; Ac[ks][1] = a0.y * am_r;
            Ac[ks][2] = a0.z * am_r; Ac[ks][3] = a0.w * am_r;
            Ac[ks][4] = a1.x * am_r; Ac[ks][5] = a1.y * am_r;
            Ac[ks][6] = a1.z * am_r; Ac[ks][7] = a1.w * am_r;
        }
        Afrag FC; splitA(Ac, FC);
        GEMM(3, FC, 1, acc1);
    }
    // h = relu(acc1 + b1) -> TS (t0 dead; own rows/cols only)
#pragma unroll
    for (int tl = 0; tl < 4; ++tl)
#pragma unroll
        for (int rr = 0; rr < 4; ++rr) {
            const int col = 16 * (4 * colh + tl) + c;
            TS[hr + rr][col] = f2h(fmaxf(acc1[tl][rr] + b1S[col], 0.0f));
        }
    __syncthreads();                     // buf0(w2) ready, h visible

    {
        float Ac[4][8];
#pragma unroll
        for (int ks = 0; ks < 4; ++ks)
#pragma unroll
            for (int j = 0; j < 8; ++j)
                Ac[ks][j] = h2f(TS[rowl][ks * 32 + 8 * qd + j]);
        Afrag FC; splitA(Ac, FC);
        f32x4 acc2[4] = {};
        GEMM(4, FC, 0, acc2);
        __syncthreads();                 // all h reads done before synth overwrite
#pragma unroll
        for (int tl = 0; tl < 4; ++tl)
#pragma unroll
            for (int rr = 0; rr < 4; ++rr) {
                const int col = 16 * (4 * colh + tl) + c;
                TS[hr + rr][col] = f2h(acc2[tl][rr] + b2S[col]);
            }
    }
    __syncthreads();                     // synth visible

    // ---- gate, update, norm, active: 8 threads/token, 16 elems each ----
    const int tok = tid >> 3, d0 = (tid & 7) * 16;
    const float am = actS[tok];
    const float* cp = curr + (size_t)(tok0 + tok) * DH + d0;
    float cv[16];
#pragma unroll
    for (int t = 0; t < 4; ++t) {
        float4 vv = *(const float4*)(cp + t * 4);
        cv[t * 4] = vv.x; cv[t * 4 + 1] = vv.y; cv[t * 4 + 2] = vv.z; cv[t * 4 + 3] = vv.w;
    }
    float srow[16];
#pragma unroll
    for (int e = 0; e < 16; ++e) srow[e] = h2f(TS[tok][d0 + e]);
    float gp = 0.0f;
#pragma unroll
    for (int e = 0; e < 16; ++e)
        gp += cv[e] * am * gwS[d0 + e] + srow[e] * gwS[128 + d0 + e];
    gp += __shfl_xor(gp, 1, 8);
    gp += __shfl_xor(gp, 2, 8);
    gp += __shfl_xor(gp, 4, 8);
    const float gate = 1.0f / (1.0f + __expf(-(gp + gbf)));
    float ss = 0.0f; float up[16];
#pragma unroll
    for (int e = 0; e < 16; ++e) {
        float u = gate * (srow[e] - cv[e] * am) * 0.1f;
        up[e] = u; ss += u * u;
    }
    ss += __shfl_xor(ss, 1, 8);
    ss += __shfl_xor(ss, 2, 8);
    ss += __shfl_xor(ss, 4, 8);
    const bool stable = sqrtf(ss) < 0.1f;

    if (last) {
        size_t off = (size_t)(tok0 + tok) * DH + d0;
        if (isb) {
            __hip_bfloat16* op = (__hip_bfloat16*)dout + off;
#pragma unroll
            for (int e = 0; e < 16; ++e) op[e] = __float2bfloat16(cv[e] + up[e]);
        } else {
            float* op = (float*)dout + off;
#pragma unroll
            for (int t = 0; t < 4; ++t)
                *(float4*)(op + t * 4) = make_float4(cv[t * 4] + up[t * 4], cv[t * 4 + 1] + up[t * 4 + 1],
                                                     cv[t * 4 + 2] + up[t * 4 + 2], cv[t * 4 + 3] + up[t * 4 + 3]);
        }
    } else {
        float* op = cur_out + (size_t)(tok0 + tok) * DH + d0;
#pragma unroll
        for (int t = 0; t < 4; ++t)
            *(float4*)(op + t * 4) = make_float4(cv[t * 4] + up[t * 4], cv[t * 4 + 1] + up[t * 4 + 1],
                                                 cv[t * 4 + 2] + up[t * 4 + 2], cv[t * 4 + 3] + up[t * 4 + 3]);
    }
    const int newact = (am > 0.0f && !stable) ? 1 : 0;
    if ((tid & 7) == 0) {
        active[tok0 + tok] = newact;
        if (newact) atomicAdd(&blkcnt, 1);
    }
    __syncthreads();
    if (tid == 0 && blkcnt > 0) atomicAdd(&counts[r + 1], blkcnt);
}

extern "C" void kernel_launch(void* const* d_in, const int* in_sizes, int n_in,
                              void* d_out, int out_size, void* d_ws, size_t ws_size,
                              hipStream_t stream) {
    const void* x  = d_in[0];
    const void* wq = d_in[1];
    const void* wk = d_in[2];
    const void* wv = d_in[3];
    const void* tw = d_in[4];
    const void* tb = d_in[5];
    const void* ab = d_in[6];
    const void* w1 = d_in[7];
    const void* b1 = d_in[8];
    const void* w2 = d_in[9];
    const void* b2 = d_in[10];
    const void* gw = d_in[11];
    const void* gb = d_in[12];

    u32* ws = (u32*)d_ws;
    const size_t N1 = (size_t)BS_ * DH;
    // base layout (~24 MiB): qp | kp | vp | active | counts | flag
    u32* qp = ws;
    u32* kp = ws + N1;        // K MFMA-frags (4 MB used of 8 MB region)
    u32* vp = ws + 2 * N1;    // V MFMA-frags (4 MB used of 8 MB region)
    int* active = (int*)(ws + 3 * N1);
    int* counts = active + BS_;
    int* flag   = counts + 4;
    float* cur0  = (float*)qp;    // small-ws path only
    float* cur_r = (float*)kp;    // overwrites dead K-frags after attn
    // split-KV x4 extension (f16 partials), ends at 42.2 MB <= 42.3 MB guarantee
    u16* Opart16 = (u16*)(ws + 3 * N1 + 32768);
    u16* lpart16 = (u16*)(ws + 5 * N1 + 32768);
    const bool big_ws = ws_size >= (size_t)42300000;        // constant across calls
    // prepacked QKV W: transient in Opart region (dead before attention writes it)
    u32x4* wpk = (u32x4*)(ws + 3 * N1 + 32768);
    // vp region after attention (V-frags dead): pkRW at base (320 KB), T0 cache at +512 KB (4 MB)
    u32x4* pkRW = (u32x4*)vp;
    u16*   T0c  = (u16*)(vp + 131072);
    u32x4* kfragP = (u32x4*)kp;
    u32x4* vfragP = (u32x4*)vp;

    init_kernel<<<dim3(BS_ / 256), 256, 0, stream>>>(x, flag, active, counts);
    prepack_w_kernel<<<dim3(192), 256, 0, stream>>>(wq, wk, wv, flag, wpk);
    qkv_kernel<<<dim3(BS_ / 64, 1, 3), 512, 0, stream>>>(x, wpk, flag, qp, kfragP, vfragP);
    if (big_ws) {
        attn_split_kernel<<<dim3(S_ / 64, B_, 4), 256, 0, stream>>>(qp, kfragP, vfragP, Opart16, lpart16);
    } else {
        attn_kernel<<<dim3(S_ / 64, B_), 256, 0, stream>>>(qp, kfragP, vfragP, cur0);
    }
    prepack_rw_kernel<<<dim3(40), 256, 0, stream>>>(tw, w1, w2, flag, pkRW);
    // round 0: fused combine + round math + T0 cache
    round0_kernel<<<dim3(BS_ / 16), 256, 0, stream>>>(
        cur0, Opart16, lpart16, pkRW, T0c, tb, ab, b1, b2, gw, gb,
        flag, active, counts, cur_r, big_ws ? 1 : 0);
    round_kernel<<<dim3(BS_ / 32), 256, 0, stream>>>(
        cur_r, pkRW, T0c, tb, ab, b1, b2, gw, gb, flag, active, counts, 1, cur_r, nullptr);
    round_kernel<<<dim3(BS_ / 32), 256, 0, stream>>>(
        cur_r, pkRW, T0c, tb, ab, b1, b2, gw, gb, flag, active, counts, 2, cur_r, d_out);
}

// Round 19
// 253.407 us; speedup vs baseline: 1.1337x; 1.1337x over previous
//
#include <hip/hip_runtime.h>
#include <hip/hip_bf16.h>

#define B_   8
#define S_   2048
#define DM   1024
#define DH   128
#define BS_  16384
#define SCALE_  0.08838834764831845f
#define SCALE2_ 0.12751744f   // SCALE * log2(e)

typedef unsigned short u16;
typedef unsigned int   u32;
typedef _Float16 half8 __attribute__((ext_vector_type(8)));
typedef __bf16   bf16x8 __attribute__((ext_vector_type(8)));
typedef float    f32x4 __attribute__((ext_vector_type(4)));
typedef u32      u32x4 __attribute__((ext_vector_type(4)));

union H8 { u32x4 v; u32 u[4]; half8 h; bf16x8 b; };

__device__ __forceinline__ float bf2f(u16 u) {
    union { u32 i; float f; } w; w.i = ((u32)u) << 16; return w.f;
}
__device__ __forceinline__ void unpack8(uint4 v, float* f) {
    f[0] = bf2f(v.x & 0xffff); f[1] = bf2f(v.x >> 16);
    f[2] = bf2f(v.y & 0xffff); f[3] = bf2f(v.y >> 16);
    f[4] = bf2f(v.z & 0xffff); f[5] = bf2f(v.z >> 16);
    f[6] = bf2f(v.w & 0xffff); f[7] = bf2f(v.w >> 16);
}
__device__ __forceinline__ float ldE(const void* b, size_t i, int isbf16) {
    return isbf16 ? bf2f(((const u16*)b)[i]) : ((const float*)b)[i];
}
__device__ __forceinline__ void ld8(const void* b, size_t i, int isbf16, float* f) {
    if (isbf16) {
        unpack8(*(const uint4*)((const u16*)b + i), f);
    } else {
        float4 a = *(const float4*)((const float*)b + i);
        float4 c = *(const float4*)((const float*)b + i + 4);
        f[0] = a.x; f[1] = a.y; f[2] = a.z; f[3] = a.w;
        f[4] = c.x; f[5] = c.y; f[6] = c.z; f[7] = c.w;
    }
}
// fp32 -> packed (f16 hi << 16) | f16 lo  (2-term split, ~22 mantissa bits)
__device__ __forceinline__ u32 f2pk(float v) {
    _Float16 h = (_Float16)v;
    _Float16 l = (_Float16)(v - (float)h);
    union { _Float16 f; u16 u; } a, b; a.f = h; b.f = l;
    return ((u32)a.u << 16) | (u32)b.u;
}
// 8 floats -> pair-packed hi/lo frag u32x4
__device__ __forceinline__ void split8(const float* f, u32x4& hi, u32x4& lo) {
    u32 H[8], L[8];
#pragma unroll
    for (int j = 0; j < 8; ++j) {
        _Float16 h = (_Float16)f[j];
        _Float16 l = (_Float16)(f[j] - (float)h);
        union { _Float16 x; u16 u; } a, b; a.x = h; b.x = l;
        H[j] = a.u; L[j] = b.u;
    }
    hi = (u32x4){H[0] | (H[1] << 16), H[2] | (H[3] << 16), H[4] | (H[5] << 16), H[6] | (H[7] << 16)};
    lo = (u32x4){L[0] | (L[1] << 16), L[2] | (L[3] << 16), L[4] | (L[5] << 16), L[6] | (L[7] << 16)};
}
__device__ __forceinline__ u32 permHI(u32 eB, u32 eA) { return __builtin_amdgcn_perm(eB, eA, 0x07060302u); }
__device__ __forceinline__ u16 f2h(float v) { union { _Float16 f; u16 u; } a; a.f = (_Float16)v; return a.u; }
__device__ __forceinline__ float h2f(u16 u) { union { _Float16 f; u16 u; } a; a.u = u; return (float)a.f; }

// ---------------- init: dtype detect + active mask + round counters ----------------
__global__ void init_kernel(const void* x, int* flag, int* active, int* counts) {
    int i = blockIdx.x * 256 + threadIdx.x;
    if (i < BS_) active[i] = 1;
    if (i < 4) counts[i] = (i == 0) ? BS_ : 0;
    if (i == 0) {
        const u16* w = (const u16*)x;
        int sane = 0;
        for (int t = 0; t < 256; ++t) {
            int e = (w[2 * t] >> 7) & 0xFF;
            if (e >= 100 && e <= 135) ++sane;
        }
        *flag = (sane >= 192) ? 1 : 0;   // 1 = bf16, 0 = fp32
    }
}

// ---------------- prepack W into MFMA fragment layout ----------------
// bf16 path: hi slot = raw bf16 pairs (lo unused). fp32 path: f16 hi/lo split.
__global__ __launch_bounds__(256) void prepack_w_kernel(
    const void* __restrict__ wq, const void* __restrict__ wk, const void* __restrict__ wv,
    const int* __restrict__ flag, u32x4* __restrict__ wpk)
{
    const int isb = *flag;
    const int gid = blockIdx.x * 256 + threadIdx.x;
    const int l  = gid & 63;
    const int t  = (gid >> 6) & 7;
    const int ks = (gid >> 9) & 31;
    const int z  = gid >> 14;
    const void* W = (z == 0) ? wq : (z == 1) ? wk : wv;
    const int row = 16 * t + (l & 15);
    const int k0  = ks * 32 + 8 * (l >> 4);
    const size_t base = ((((size_t)z * 32 + ks) * 16) + 2 * t) * 64 + l;
    if (isb) {
        uint4 v = *(const uint4*)((const u16*)W + (size_t)row * DM + k0);
        wpk[base] = (u32x4){v.x, v.y, v.z, v.w};
    } else {
        float f[8];
        ld8(W, (size_t)row * DM + k0, 0, f);
        u32x4 hi, lo;
        split8(f, hi, lo);
        wpk[base]      = hi;
        wpk[base + 64] = lo;
    }
}

// ---------------- MFMA QKV (R11 form): 64 rows/block, BK=64 staged, grid (256,1,3) ----------------
// z=0: Q packs. z=1: K MFMA-frags. z=2: V MFMA-frags.
__global__ __launch_bounds__(256) void qkv_kernel(
    const void* __restrict__ x, const u32x4* __restrict__ wpk,
    const int* __restrict__ flag, u32* __restrict__ qout,
    u32x4* __restrict__ kfrag, u32x4* __restrict__ vfrag)
{
    const int isb = *flag;
    const int z = blockIdx.z;
    // XCD swizzle (bijective on [0,256)): consecutive x-tiles stay on one XCD
    const int bx = blockIdx.x;
    const int m0 = ((bx & 7) * 32 + (bx >> 3)) * 64;
    const int tid = threadIdx.x;
    const int wave = tid >> 6, lane = tid & 63;
    const int qd = lane >> 4, c = lane & 15;

    __shared__ u32x4 WLraw[2][16][64];   // 32 KB; TS overlays after the loop
    // views
    u32x4 (*WLb)[2][8][64] = (u32x4(*)[2][8][64])WLraw;   // bf16: [buf][ksub][t][lane]
    u32x4 (*WLf)[8][2][64] = (u32x4(*)[8][2][64])WLraw;   // fp32: [buf][t][plane][lane]
    u16 (*TS)[136] = (u16(*)[136])WLraw;                  // 17.4 KB overlay

    const u32x4* wz = wpk + (size_t)z * (32 * 16 * 64);
    const size_t arow = (size_t)(m0 + wave * 16 + c) * DM + 8 * qd;

// bf16 BK=64 stage: iter i covers ks=2i,2i+1; 16 hi slabs, 4 per wave
#define STAGE2(i_, b_)                                                            \
    {                                                                             \
        _Pragma("unroll")                                                         \
        for (int _j = 0; _j < 4; ++_j) {                                          \
            const int _g = wave * 4 + _j, _ksub = _g >> 3, _t = _g & 7;           \
            __builtin_amdgcn_global_load_lds(                                     \
                (const __attribute__((address_space(1))) u32*)(                   \
                    wz + ((size_t)(2 * (i_) + _ksub) * 16 + 2 * _t) * 64 + lane), \
                (__attribute__((address_space(3))) u32*)&WLb[b_][_ksub][_t][0],   \
                16, 0, 0);                                                        \
        }                                                                         \
    }
// fp32 stage (1 K-step): 16 slabs (8 tiles x hi/lo), 4 per wave
#define STAGE_W(ks_, b_)                                                          \
    {                                                                             \
        const u32x4* _src = wz + ((size_t)(ks_) * 16 + 4 * wave) * 64 + lane;     \
        _Pragma("unroll")                                                         \
        for (int _j = 0; _j < 4; ++_j) {                                          \
            __builtin_amdgcn_global_load_lds(                                     \
                (const __attribute__((address_space(1))) u32*)(_src + _j * 64),   \
                (__attribute__((address_space(3))) u32*)&WLf[b_][2 * wave + (_j >> 1)][_j & 1][0], \
                16, 0, 0);                                                        \
        }                                                                         \
    }

    f32x4 acc[8] = {};

    if (isb) {
        const u16* xb = (const u16*)x;
        uint4 A0 = *(const uint4*)(xb + arow);
        uint4 A1 = *(const uint4*)(xb + arow + 32);
        STAGE2(0, 0);
        uint4 A0n = *(const uint4*)(xb + arow + 64);
        uint4 A1n = *(const uint4*)(xb + arow + 96);
        __syncthreads();
        for (int i = 0; i < 16; ++i) {
            const int cb = i & 1;
            if (i + 1 < 16) STAGE2(i + 1, cb ^ 1);
            H8 Ah0; Ah0.v = (u32x4){A0.x, A0.y, A0.z, A0.w};
            H8 Ah1; Ah1.v = (u32x4){A1.x, A1.y, A1.z, A1.w};
#pragma unroll
            for (int t = 0; t < 8; ++t) {
                H8 bh; bh.v = WLb[cb][0][t][lane];
                acc[t] = __builtin_amdgcn_mfma_f32_16x16x32_bf16(Ah0.b, bh.b, acc[t], 0, 0, 0);
            }
#pragma unroll
            for (int t = 0; t < 8; ++t) {
                H8 bh; bh.v = WLb[cb][1][t][lane];
                acc[t] = __builtin_amdgcn_mfma_f32_16x16x32_bf16(Ah1.b, bh.b, acc[t], 0, 0, 0);
            }
            A0 = A0n; A1 = A1n;
            if (i + 2 < 16) {
                A0n = *(const uint4*)(xb + arow + (size_t)(i + 2) * 64);
                A1n = *(const uint4*)(xb + arow + (size_t)(i + 2) * 64 + 32);
            }
            __syncthreads();
        }
    } else {
        float Ar[8], Arn[8];
        ld8(x, arow, 0, Ar);
        STAGE_W(0, 0);
        ld8(x, arow + 32, 0, Arn);
        __syncthreads();
        for (int ks = 0; ks < 32; ++ks) {
            const int cb = ks & 1;
            if (ks + 1 < 32) STAGE_W(ks + 1, cb ^ 1);
            H8 Ah, Al;
            split8(Ar, Ah.v, Al.v);
#pragma unroll
            for (int t = 0; t < 8; ++t) {
                H8 bh, bl;
                bh.v = WLf[cb][t][0][lane]; bl.v = WLf[cb][t][1][lane];
                acc[t] = __builtin_amdgcn_mfma_f32_16x16x32_f16(Al.h, bh.h, acc[t], 0, 0, 0);
                acc[t] = __builtin_amdgcn_mfma_f32_16x16x32_f16(Ah.h, bl.h, acc[t], 0, 0, 0);
                acc[t] = __builtin_amdgcn_mfma_f32_16x16x32_f16(Ah.h, bh.h, acc[t], 0, 0, 0);
            }
#pragma unroll
            for (int j = 0; j < 8; ++j) Ar[j] = Arn[j];
            if (ks + 2 < 32) ld8(x, arow + (size_t)(ks + 2) * 32, 0, Arn);
            __syncthreads();
        }
    }
#undef STAGE2
#undef STAGE_W

    if (z == 0) {
#pragma unroll
        for (int r = 0; r < 4; ++r) {
            const int row = m0 + wave * 16 + qd * 4 + r;
            u32* op = qout + (size_t)row * DH + c;
#pragma unroll
            for (int t = 0; t < 8; ++t) op[t * 16] = f2pk(acc[t][r]);
        }
    } else {
        // stage [key(local)][dh] f16 tile (overlays WL; loop's final barrier protects)
#pragma unroll
        for (int t = 0; t < 8; ++t)
#pragma unroll
            for (int r = 0; r < 4; ++r)
                TS[wave * 16 + qd * 4 + r][16 * t + c] = f2h(acc[t][r]);
        __syncthreads();
        if (z == 1) {
            // kfrag[kt16][ks][lane] = K[kt16*16 + (lane&15)][ks*32 + 8*(lane>>4) + j]
#pragma unroll
            for (int i = 0; i < 4; ++i) {
                const int f = tid + 256 * i;          // 0..1023
                const int lf = f & 63, ks = (f >> 6) & 3, sub = f >> 8;
                const int key = sub * 16 + (lf & 15);
                const int d0  = ks * 32 + 8 * (lf >> 4);
                u32 w[4];
#pragma unroll
                for (int q = 0; q < 4; ++q)
                    w[q] = (u32)TS[key][d0 + 2 * q] | ((u32)TS[key][d0 + 2 * q + 1] << 16);
                kfrag[((size_t)(m0 / 16 + sub) * 4 + ks) * 64 + lf] = (u32x4){w[0], w[1], w[2], w[3]};
            }
        } else {
            // vfrag[kt32][t][lane] = V[kt32*32 + 8*(lane>>4) + j][16t + (lane&15)]
#pragma unroll
            for (int i = 0; i < 4; ++i) {
                const int f = tid + 256 * i;          // 0..1023
                const int lf = f & 63, t = (f >> 6) & 7, sub = f >> 9;
                const int kb2 = sub * 32 + 8 * (lf >> 4);
                const int dh  = 16 * t + (lf & 15);
                u32 w[4];
#pragma unroll
                for (int q = 0; q < 4; ++q)
                    w[q] = (u32)TS[kb2 + 2 * q][dh] | ((u32)TS[kb2 + 2 * q + 1][dh] << 16);
                vfrag[((size_t)(m0 / 32 + sub) * 8 + t) * 64 + lf] = (u32x4){w[0], w[1], w[2], w[3]};
            }
        }
    }
}

// ---------------- attention core: barrier-free, frags from global (L2-hot) ----------------
// PB stride 40 u16 (80 B): rows 16B-aligned -> P re-read is one ds_read_b128, conflict-free.
template <bool WRITE_PARTIAL>
__device__ __forceinline__ void attn_body(
    const u32* qp, const u32x4* __restrict__ kfrag, const u32x4* __restrict__ vfrag,
    u16* outO, u16* outL, float* cur,
    int b, int q0, int kt0, int kt1, int part)
{
    const int tid = threadIdx.x;
    const int wave = tid >> 6, lane = tid & 63;
    const int qd = lane >> 4, c = lane & 15;

    __shared__ __align__(16) u16 PB[4][640];   // per-wave P, stride 40 (wave-private)

    H8 Qh[4];
    {
        const u32* qr = qp + ((size_t)b * S_ + q0 + wave * 16 + c) * DH;
#pragma unroll
        for (int ks = 0; ks < 4; ++ks) {
            uint4 e0 = *(const uint4*)(qr + ks * 32 + qd * 8);
            uint4 e1 = *(const uint4*)(qr + ks * 32 + qd * 8 + 4);
            Qh[ks].u[0] = permHI(e0.y, e0.x); Qh[ks].u[1] = permHI(e0.w, e0.z);
            Qh[ks].u[2] = permHI(e1.y, e1.x); Qh[ks].u[3] = permHI(e1.w, e1.z);
        }
    }

    f32x4 O[8] = {};
    float lsum[4] = {};

    const u32x4* kb0 = kfrag + (size_t)b * 128 * 256;   // kt16 stride = 4*64
    const u32x4* vb0 = vfrag + (size_t)b * 64 * 512;    // kt32 stride = 8*64

    for (int kt = kt0; kt < kt1; ++kt) {
        const u32x4* kf = kb0 + (size_t)kt * 512;       // two kt16 blocks
        const u32x4* vf = vb0 + (size_t)kt * 512;

        f32x4 S0 = {}, S1 = {};
        __builtin_amdgcn_s_setprio(1);
#pragma unroll
        for (int ks = 0; ks < 4; ++ks) {
            H8 kh;
            kh.v = kf[ks * 64 + lane];
            S0 = __builtin_amdgcn_mfma_f32_16x16x32_f16(Qh[ks].h, kh.h, S0, 0, 0, 0);
            kh.v = kf[256 + ks * 64 + lane];
            S1 = __builtin_amdgcn_mfma_f32_16x16x32_f16(Qh[ks].h, kh.h, S1, 0, 0, 0);
        }
        __builtin_amdgcn_s_setprio(0);

        u16* pw = PB[wave];
#pragma unroll
        for (int r = 0; r < 4; ++r) {
            float e0 = exp2f(fmaf(S0[r], SCALE2_, -4.0f));
            float e1 = exp2f(fmaf(S1[r], SCALE2_, -4.0f));
            lsum[r] += e0 + e1;
            pw[(4 * qd + r) * 40 + c]      = f2h(e0);
            pw[(4 * qd + r) * 40 + 16 + c] = f2h(e1);
        }

        uint4 ev = *(const uint4*)&pw[c * 40 + 8 * qd];   // one b128: P row c, keys 8qd..8qd+7
        H8 Ph;
        Ph.u[0] = ev.x; Ph.u[1] = ev.y; Ph.u[2] = ev.z; Ph.u[3] = ev.w;

        __builtin_amdgcn_s_setprio(1);
#pragma unroll
        for (int t = 0; t < 8; ++t) {
            H8 vh;
            vh.v = vf[t * 64 + lane];
            O[t] = __builtin_amdgcn_mfma_f32_16x16x32_f16(Ph.h, vh.h, O[t], 0, 0, 0);
        }
        __builtin_amdgcn_s_setprio(0);
    }

    if (WRITE_PARTIAL) {
        float lred[4];
#pragma unroll
        for (int r = 0; r < 4; ++r) {
            float l = lsum[r];
            l += __shfl_xor(l, 1); l += __shfl_xor(l, 2);
            l += __shfl_xor(l, 4); l += __shfl_xor(l, 8);
            lred[r] = l;
        }
        const size_t rb = (size_t)b * S_ + q0 + wave * 16 + 4 * qd;
        u16* Op = outO + (size_t)part * ((size_t)BS_ * DH);
#pragma unroll
        for (int t = 0; t < 8; ++t)
#pragma unroll
            for (int r = 0; r < 4; ++r)
                Op[(rb + r) * DH + t * 16 + c] = f2h(O[t][r]);
        if (c == 0) {
            u16* lp = outL + (size_t)part * BS_;
#pragma unroll
            for (int r = 0; r < 4; ++r) lp[rb + r] = f2h(lred[r]);
        }
    } else {
        float linv[4];
#pragma unroll
        for (int r = 0; r < 4; ++r) {
            float l = lsum[r];
            l += __shfl_xor(l, 1); l += __shfl_xor(l, 2);
            l += __shfl_xor(l, 4); l += __shfl_xor(l, 8);
            linv[r] = 1.0f / l;
        }
        const size_t rb = (size_t)b * S_ + q0 + wave * 16 + 4 * qd;
#pragma unroll
        for (int t = 0; t < 8; ++t)
#pragma unroll
            for (int r = 0; r < 4; ++r)
                cur[(rb + r) * DH + t * 16 + c] = O[t][r] * linv[r];
    }
}

// single-pass fallback: grid (32, 8). XCD swizzle: batch = rid&7 (bijective).
__global__ __launch_bounds__(256) void attn_kernel(
    const u32* qp, const u32x4* __restrict__ kfrag, const u32x4* __restrict__ vfrag, float* cur)
{
    const int rid = blockIdx.x + 32 * blockIdx.y;
    attn_body<false>(qp, kfrag, vfrag, nullptr, nullptr, cur,
                     rid & 7, ((rid >> 3) & 31) * 64, 0, S_ / 32, 0);
}

// split-KV x4: grid (32, 8, 4) = 1024 blocks. batch = rid&7 per XCD.
__global__ __launch_bounds__(256) void attn_split_kernel(
    const u32* qp, const u32x4* __restrict__ kfrag, const u32x4* __restrict__ vfrag,
    u16* __restrict__ Opart, u16* __restrict__ lpart)
{
    const int rid = blockIdx.x + 32 * (blockIdx.y + 8 * blockIdx.z);
    const int b    = rid & 7;
    const int qx   = (rid >> 3) & 31;
    const int part = rid >> 8;
    const int quart = S_ / 128;   // 16 tiles per part
    attn_body<true>(qp, kfrag, vfrag, Opart, lpart, nullptr,
                    b, qx * 64, part * quart, (part + 1) * quart, part);
}

// ---------------- prepack round weights (straight repack, no algebra) ----------------
// mats: 0=tw, 1=w1[:,0:128], 2=w1[:,128:256], 3=w1[:,256:384], 4=w2
__global__ __launch_bounds__(256) void prepack_rw_kernel(
    const void* __restrict__ tw, const void* __restrict__ w1, const void* __restrict__ w2,
    const int* __restrict__ flag, u32x4* __restrict__ pk)
{
    const int isb = *flag;
    const int gid = blockIdx.x * 256 + threadIdx.x;   // 10240 total
    const int l = gid & 63, t = (gid >> 6) & 7, ks = (gid >> 9) & 3, mat = gid >> 11;
    const int row = 16 * t + (l & 15);
    const int k0  = ks * 32 + 8 * (l >> 4);
    float f[8];
    if (mat == 0)      ld8(tw, (size_t)row * DH + k0, isb, f);
    else if (mat <= 3) ld8(w1, (size_t)row * 384 + (mat - 1) * 128 + k0, isb, f);
    else               ld8(w2, (size_t)row * DH + k0, isb, f);
    u32x4 hi, lo;
    split8(f, hi, lo);
    const size_t base = (((size_t)mat * 4 + ks) * 16 + 2 * t) * 64 + l;
    pk[base] = hi; pk[base + 64] = lo;
}

// pre-split A fragments
struct Afrag { H8 h[4], l[4]; };
__device__ __forceinline__ void splitA(const float (&A)[4][8], Afrag& F) {
#pragma unroll
    for (int ks = 0; ks < 4; ++ks) split8(A[ks], F.h[ks].v, F.l[ks].v);
}

// ---------------- round 0: fused combine + dialectic round, 16 tokens/block, grid 1024 ----------
// Builds combined cur0 in LDS (CS, f32, bit-identical to old combine_kernel output),
// runs round-0 math (all tokens active, am=1), caches t0 to T0 for rounds 1-2.
__global__ __launch_bounds__(256) void round0_kernel(
    const float* __restrict__ cur0g,
    const u16* __restrict__ Opart, const u16* __restrict__ lpart,
    const u32x4* __restrict__ pk, u16* __restrict__ T0,
    const void* __restrict__ tb, const void* __restrict__ ab,
    const void* __restrict__ b1, const void* __restrict__ b2,
    const void* __restrict__ gw, const void* __restrict__ gb,
    const int* __restrict__ flag, int* active, int* counts,
    float* cur_out, int combine)
{
    const int isb = *flag;
    const int tok0 = blockIdx.x * 16;
    const int tid = threadIdx.x;
    const int wave = tid >> 6, lane = tid & 63;
    const int qd = lane >> 4, c = lane & 15;

    __shared__ u32x4 WB[2][2][8][64];   // 32 KB: [buf][kl(or plane)][t][lane]
    __shared__ u16 TS[16][132];         // t0 -> h -> synth (f16)
    __shared__ float CS[16][128];       // combined cur0 rows (f32, 8 KB)
    __shared__ float tbS[128], abS[128], b1S[128], b2S[128], gwS[256];
    __shared__ int blkcnt;

    auto stageBh = [&](int mat, int h) {
#pragma unroll
        for (int j = 0; j < 4; ++j) {
            const int g = wave * 4 + j, kl = g >> 3, t = g & 7;
            __builtin_amdgcn_global_load_lds(
                (const __attribute__((address_space(1))) u32*)(
                    pk + (((size_t)mat * 4 + 2 * h + kl) * 16 + 2 * t) * 64 + lane),
                (__attribute__((address_space(3))) u32*)&WB[h][kl][t][0],
                16, 0, 0);
        }
    };
    auto gemmBh = [&](const Afrag& F, int h, f32x4 (&acc)[2]) {
#pragma unroll
        for (int kl = 0; kl < 2; ++kl) {
            const int ks = 2 * h + kl;
#pragma unroll
            for (int tl = 0; tl < 2; ++tl) {
                H8 bh; bh.v = WB[h][kl][2 * wave + tl][lane];
                acc[tl] = __builtin_amdgcn_mfma_f32_16x16x32_f16(F.l[ks].h, bh.h, acc[tl], 0, 0, 0);
                acc[tl] = __builtin_amdgcn_mfma_f32_16x16x32_f16(F.h[ks].h, bh.h, acc[tl], 0, 0, 0);
            }
        }
    };
    auto stageFq = [&](int mat, int q, int buf) {
#pragma unroll
        for (int j = 0; j < 4; ++j) {
            const int g = wave * 4 + j, p = g & 1, t = g >> 1;
            __builtin_amdgcn_global_load_lds(
                (const __attribute__((address_space(1))) u32*)(
                    pk + (((size_t)mat * 4 + q) * 16 + 2 * t + p) * 64 + lane),
                (__attribute__((address_space(3))) u32*)&WB[buf][p][t][0],
                16, 0, 0);
        }
    };
    auto gemmFq = [&](const Afrag& F, int q, int buf, f32x4 (&acc)[2]) {
#pragma unroll
        for (int tl = 0; tl < 2; ++tl) {
            H8 bh, bl;
            bh.v = WB[buf][0][2 * wave + tl][lane];
            bl.v = WB[buf][1][2 * wave + tl][lane];
            acc[tl] = __builtin_amdgcn_mfma_f32_16x16x32_f16(F.l[q].h, bh.h, acc[tl], 0, 0, 0);
            acc[tl] = __builtin_amdgcn_mfma_f32_16x16x32_f16(F.h[q].h, bl.h, acc[tl], 0, 0, 0);
            acc[tl] = __builtin_amdgcn_mfma_f32_16x16x32_f16(F.h[q].h, bh.h, acc[tl], 0, 0, 0);
        }
    };
    auto GEMMF = [&](int mat, const Afrag& F, f32x4 (&acc)[2]) {
        for (int q = 0; q < 4; ++q) {
            stageFq(mat, q, q & 1);
            __syncthreads();
            gemmFq(F, q, q & 1, acc);
            __syncthreads();
        }
    };

    const int hr = 4 * qd;
    const int rowl = c;

    auto writeTS = [&](const f32x4 (&acc)[2], const float* bias, bool relu) {
#pragma unroll
        for (int tl = 0; tl < 2; ++tl)
#pragma unroll
            for (int rr = 0; rr < 4; ++rr) {
                const int col = 16 * (2 * wave + tl) + c;
                float v = acc[tl][rr] + (bias ? bias[col] : 0.0f);
                TS[hr + rr][col] = f2h(relu ? fmaxf(v, 0.0f) : v);
            }
    };
    auto buildA1 = [&](Afrag& F) {
        float Ac[4][8];
#pragma unroll
        for (int ks = 0; ks < 4; ++ks)
#pragma unroll
            for (int j = 0; j < 8; ++j)
                Ac[ks][j] = CS[rowl][ks * 32 + 8 * qd + j];
        splitA(Ac, F);
    };
    auto buildAt = [&](Afrag& F) {
        float Ac[4][8];
#pragma unroll
        for (int ks = 0; ks < 4; ++ks)
#pragma unroll
            for (int j = 0; j < 8; ++j) {
                const int k = ks * 32 + 8 * qd + j;
                Ac[ks][j] = h2f(TS[rowl][k]) + tbS[k];
            }
        splitA(Ac, F);
    };
    auto buildAa = [&](Afrag& F) {
        float Ac[4][8];
#pragma unroll
        for (int ks = 0; ks < 4; ++ks)
#pragma unroll
            for (int j = 0; j < 8; ++j) {
                const int k = ks * 32 + 8 * qd + j;
                Ac[ks][j] = abS[k] - h2f(TS[rowl][k]);
            }
        splitA(Ac, F);
    };
    auto buildAh = [&](Afrag& F) {
        float Ac[4][8];
#pragma unroll
        for (int ks = 0; ks < 4; ++ks)
#pragma unroll
            for (int j = 0; j < 8; ++j)
                Ac[ks][j] = h2f(TS[rowl][ks * 32 + 8 * qd + j]);
        splitA(Ac, F);
    };

    // ---- constants + combined cur0 into CS (8 elems/thread) ----
    if (tid < 128) {
        tbS[tid] = ldE(tb, tid, isb); abS[tid] = ldE(ab, tid, isb);
        b1S[tid] = ldE(b1, tid, isb); b2S[tid] = ldE(b2, tid, isb);
    }
    gwS[tid] = ldE(gw, tid, isb);
    if (tid == 0) blkcnt = 0;
    const float gbf = ldE(gb, 0, isb);
    {
        const int row = tid >> 4, d0 = (tid & 15) * 8;
        float a8[8];
        if (combine) {
            const size_t grow = (size_t)(tok0 + row);
            const float lt = h2f(lpart[grow]) + h2f(lpart[BS_ + grow])
                           + h2f(lpart[2 * BS_ + grow]) + h2f(lpart[3 * BS_ + grow]);
            const float linv = 1.0f / lt;
            float acc[8] = {};
            const size_t N1 = (size_t)BS_ * DH;
#pragma unroll
            for (int p = 0; p < 4; ++p) {
                const u16* op = Opart + (size_t)p * N1 + grow * DH + d0;
                uint4 v0 = *(const uint4*)op;
                const u32 w[4] = {v0.x, v0.y, v0.z, v0.w};
#pragma unroll
                for (int j = 0; j < 4; ++j) {
                    acc[2 * j]     += h2f((u16)(w[j] & 0xffff));
                    acc[2 * j + 1] += h2f((u16)(w[j] >> 16));
                }
            }
#pragma unroll
            for (int e = 0; e < 8; ++e) a8[e] = acc[e] * linv;
        } else {
            const float* cr = cur0g + (size_t)(tok0 + row) * DH + d0;
            float4 v0 = *(const float4*)cr;
            float4 v1 = *(const float4*)(cr + 4);
            a8[0] = v0.x; a8[1] = v0.y; a8[2] = v0.z; a8[3] = v0.w;
            a8[4] = v1.x; a8[5] = v1.y; a8[6] = v1.z; a8[7] = v1.w;
        }
#pragma unroll
        for (int e = 0; e < 8; ++e) CS[row][d0 + e] = a8[e];
    }

    if (isb) {
        stageBh(0, 0);
        __syncthreads();                 // WB0(tw.h0) + CS + consts
        Afrag FA; buildA1(FA);
        stageBh(0, 1);
        f32x4 accT[2] = {};
        gemmBh(FA, 0, accT);
        __syncthreads();                 // WB1(tw.h1)
        stageBh(1, 0);
        gemmBh(FA, 1, accT);
        writeTS(accT, nullptr, false);   // t0
        __syncthreads();                 // WB0(w1a.h0) + TS(t0)
        for (int i = tid; i < 16 * 64; i += 256) {
            const int row = i >> 6, c2 = (i & 63) * 2;
            *(u32*)&T0[(size_t)(tok0 + row) * DH + c2] = *(const u32*)&TS[row][c2];
        }
        f32x4 acc1[2] = {};
        {   // at @ w1a
            Afrag FC; buildAt(FC);
            stageBh(1, 1);
            gemmBh(FC, 0, acc1);
            __syncthreads();             // WB1(w1a.h1)
            stageBh(2, 0);
            gemmBh(FC, 1, acc1);
            __syncthreads();             // WB0(w1b.h0)
        }
        {   // aa @ w1b
            Afrag FC; buildAa(FC);
            stageBh(2, 1);
            gemmBh(FC, 0, acc1);
            __syncthreads();             // WB1(w1b.h1)
            stageBh(3, 0);
            gemmBh(FC, 1, acc1);
            __syncthreads();             // WB0(w1c.h0)
        }
        {   // ac @ w1c (A = CS rows, am = 1)
            Afrag FC; buildA1(FC);
            stageBh(3, 1);
            gemmBh(FC, 0, acc1);
            __syncthreads();             // WB1(w1c.h1)
            stageBh(4, 0);
            gemmBh(FC, 1, acc1);
        }
        writeTS(acc1, b1S, true);        // h (t0 readers done >=2 barriers ago)
        __syncthreads();                 // WB0(w2.h0) + TS(h)
        {   // h @ w2
            Afrag FC; buildAh(FC);
            stageBh(4, 1);
            f32x4 acc2[2] = {};
            gemmBh(FC, 0, acc2);
            __syncthreads();             // WB1(w2.h1); separates h reads from synth write
            gemmBh(FC, 1, acc2);
            writeTS(acc2, b2S, false);   // synth
        }
        __syncthreads();                 // synth visible
    } else {
        __syncthreads();                 // CS + consts
        Afrag FA; buildA1(FA);
        f32x4 accT[2] = {};
        GEMMF(0, FA, accT);
        writeTS(accT, nullptr, false);
        __syncthreads();
        for (int i = tid; i < 16 * 64; i += 256) {
            const int row = i >> 6, c2 = (i & 63) * 2;
            *(u32*)&T0[(size_t)(tok0 + row) * DH + c2] = *(const u32*)&TS[row][c2];
        }
        f32x4 acc1[2] = {};
        { Afrag FC; buildAt(FC); GEMMF(1, FC, acc1); }
        { Afrag FC; buildAa(FC); GEMMF(2, FC, acc1); }
        { Afrag FC; buildA1(FC); GEMMF(3, FC, acc1); }
        writeTS(acc1, b1S, true);
        __syncthreads();
        {
            Afrag FC; buildAh(FC);
            f32x4 acc2[2] = {};
            GEMMF(4, FC, acc2);
            writeTS(acc2, b2S, false);
        }
        __syncthreads();
    }

    // ---- gate, update, norm, active (am = 1): 16 threads/token, 8 elems each ----
    const int tok = tid >> 4, d0g = (tid & 15) * 8;
    float cv[8];
#pragma unroll
    for (int e = 0; e < 8; ++e) cv[e] = CS[tok][d0g + e];
    float srow[8];
#pragma unroll
    for (int e = 0; e < 8; ++e) srow[e] = h2f(TS[tok][d0g + e]);
    float gp = 0.0f;
#pragma unroll
    for (int e = 0; e < 8; ++e)
        gp += cv[e] * gwS[d0g + e] + srow[e] * gwS[128 + d0g + e];
    gp += __shfl_xor(gp, 1, 16);
    gp += __shfl_xor(gp, 2, 16);
    gp += __shfl_xor(gp, 4, 16);
    gp += __shfl_xor(gp, 8, 16);
    const float gate = 1.0f / (1.0f + __expf(-(gp + gbf)));
    float ss = 0.0f; float up[8];
#pragma unroll
    for (int e = 0; e < 8; ++e) {
        float u = gate * (srow[e] - cv[e]) * 0.1f;
        up[e] = u; ss += u * u;
    }
    ss += __shfl_xor(ss, 1, 16);
    ss += __shfl_xor(ss, 2, 16);
    ss += __shfl_xor(ss, 4, 16);
    ss += __shfl_xor(ss, 8, 16);
    const bool stable = sqrtf(ss) < 0.1f;

    float* op = cur_out + (size_t)(tok0 + tok) * DH + d0g;
    *(float4*)op       = make_float4(cv[0] + up[0], cv[1] + up[1], cv[2] + up[2], cv[3] + up[3]);
    *(float4*)(op + 4) = make_float4(cv[4] + up[4], cv[5] + up[5], cv[6] + up[6], cv[7] + up[7]);
    const int newact = stable ? 0 : 1;
    if ((tid & 15) == 0) {
        active[tok0 + tok] = newact;
        if (newact) atomicAdd(&blkcnt, 1);
    }
    __syncthreads();
    if (tid == 0 && blkcnt > 0) atomicAdd(&counts[1], blkcnt);
}

// ---------------- rounds 1,2: 32 tokens/block, grid 512, dbuf stage (R15 form) ----------------
__global__ __launch_bounds__(256) void round_kernel(
    const float* curr,
    const u32x4* __restrict__ pk, const u16* __restrict__ T0,
    const void* __restrict__ tb, const void* __restrict__ ab,
    const void* __restrict__ b1, const void* __restrict__ b2,
    const void* __restrict__ gw, const void* __restrict__ gb,
    const int* __restrict__ flag, int* active, int* counts, int r,
    float* cur_out, void* dout)
{
    const int isb = *flag;
    const int tok0 = blockIdx.x * 32;
    const int tid = threadIdx.x;
    const bool last = (dout != nullptr);

    if (counts[r] <= 0) {
        if (last) {
            for (int e = tid; e < 32 * DH; e += 256) {
                size_t idx = (size_t)tok0 * DH + e;
                float v = curr[idx];
                if (isb) ((__hip_bfloat16*)dout)[idx] = __float2bfloat16(v);
                else     ((float*)dout)[idx] = v;
            }
        }
        return;
    }

    const int wave = tid >> 6, lane = tid & 63;
    const int qd = lane >> 4, c = lane & 15;
    const int rowg = wave >> 1, colh = wave & 1;

    __shared__ u32x4 WB[2][4][8][64];   // 64 KB double-buffered weight stage
    __shared__ u16 TS[32][132];         // t0 -> h -> synth (f16, 8.4 KB)
    __shared__ float actS[32], tbS[128], abS[128], b1S[128], b2S[128], gwS[256];
    __shared__ int blkcnt;

    auto stageB = [&](int mat, int buf) {
#pragma unroll
        for (int j = 0; j < 8; ++j) {
            const int g = wave * 8 + j, ks = g >> 3, t = g & 7;
            __builtin_amdgcn_global_load_lds(
                (const __attribute__((address_space(1))) u32*)(
                    pk + (((size_t)mat * 4 + ks) * 16 + 2 * t) * 64 + lane),
                (__attribute__((address_space(3))) u32*)&WB[buf][ks][t][0],
                16, 0, 0);
        }
    };
    auto stageF = [&](int mat, int h, int buf) {
#pragma unroll
        for (int j = 0; j < 8; ++j) {
            const int g = wave * 8 + j, kl = g >> 4, p = (g >> 3) & 1, t = g & 7;
            __builtin_amdgcn_global_load_lds(
                (const __attribute__((address_space(1))) u32*)(
                    pk + (((size_t)mat * 4 + 2 * h + kl) * 16 + 2 * t + p) * 64 + lane),
                (__attribute__((address_space(3))) u32*)&WB[buf][kl * 2 + p][t][0],
                16, 0, 0);
        }
    };
    auto gemmB = [&](const Afrag& F, int buf, f32x4 (&acc)[4]) {
#pragma unroll
        for (int ks = 0; ks < 4; ++ks)
#pragma unroll
            for (int tl = 0; tl < 4; ++tl) {
                H8 bh; bh.v = WB[buf][ks][4 * colh + tl][lane];
                acc[tl] = __builtin_amdgcn_mfma_f32_16x16x32_f16(F.l[ks].h, bh.h, acc[tl], 0, 0, 0);
                acc[tl] = __builtin_amdgcn_mfma_f32_16x16x32_f16(F.h[ks].h, bh.h, acc[tl], 0, 0, 0);
            }
    };
    auto gemmFh = [&](const Afrag& F, int h, int buf, f32x4 (&acc)[4]) {
#pragma unroll
        for (int kl = 0; kl < 2; ++kl) {
            const int ks = 2 * h + kl;
#pragma unroll
            for (int tl = 0; tl < 4; ++tl) {
                H8 bh, bl;
                bh.v = WB[buf][kl * 2][4 * colh + tl][lane];
                bl.v = WB[buf][kl * 2 + 1][4 * colh + tl][lane];
                acc[tl] = __builtin_amdgcn_mfma_f32_16x16x32_f16(F.l[ks].h, bh.h, acc[tl], 0, 0, 0);
                acc[tl] = __builtin_amdgcn_mfma_f32_16x16x32_f16(F.h[ks].h, bl.h, acc[tl], 0, 0, 0);
                acc[tl] = __builtin_amdgcn_mfma_f32_16x16x32_f16(F.h[ks].h, bh.h, acc[tl], 0, 0, 0);
            }
        }
    };
    auto STAGE = [&](int mat, int buf) { if (isb) stageB(mat, buf); else stageF(mat, 0, buf); };
    auto GEMM = [&](int mat, const Afrag& F, int buf, f32x4 (&acc)[4]) {
        if (isb) {
            gemmB(F, buf, acc);
        } else {
            gemmFh(F, 0, buf, acc);
            __syncthreads();
            stageF(mat, 1, buf);
            __syncthreads();
            gemmFh(F, 1, buf, acc);
        }
    };

    STAGE(1, 1);   // w1a (t0 comes from cache)
    if (tid < 32) actS[tid] = active[tok0 + tid] ? 1.0f : 0.0f;
    if (tid < 128) {
        tbS[tid] = ldE(tb, tid, isb); abS[tid] = ldE(ab, tid, isb);
        b1S[tid] = ldE(b1, tid, isb); b2S[tid] = ldE(b2, tid, isb);
    }
    gwS[tid] = ldE(gw, tid, isb);
    if (tid == 0) blkcnt = 0;
    const float gbf = ldE(gb, 0, isb);

    const int rowl = 16 * rowg + c;
    const int hr   = 16 * rowg + 4 * qd;

    // load cached t0 into TS (coalesced u32 copy: 32 rows x 64 u32)
    for (int i = tid; i < 32 * 64; i += 256) {
        const int row = i >> 6, c2 = (i & 63) * 2;
        *(u32*)&TS[row][c2] = *(const u32*)&T0[(size_t)(tok0 + row) * DH + c2];
    }
    __syncthreads();                     // buf1 ready, TS(t0) + consts visible

    STAGE(2, 0);                         // w1b
    f32x4 acc1[4] = {};
    const float am_r = actS[rowl];
    {
        float Ac[4][8];
#pragma unroll
        for (int ks = 0; ks < 4; ++ks)
#pragma unroll
            for (int j = 0; j < 8; ++j) {
                const int k = ks * 32 + 8 * qd + j;
                Ac[ks][j] = (h2f(TS[rowl][k]) + tbS[k]) * am_r;   // at
            }
        Afrag FC; splitA(Ac, FC);
        GEMM(1, FC, 1, acc1);
    }
    __syncthreads();                     // buf0 ready, buf1 free

    STAGE(3, 1);                         // w1c
    {
        float Ac[4][8];
#pragma unroll
        for (int ks = 0; ks < 4; ++ks)
#pragma unroll
            for (int j = 0; j < 8; ++j) {
                const int k = ks * 32 + 8 * qd + j;
                Ac[ks][j] = (abS[k] - h2f(TS[rowl][k])) * am_r;   // aa
            }
        Afrag FC; splitA(Ac, FC);
        GEMM(2, FC, 0, acc1);
    }
    __syncthreads();                     // buf1 ready; all TS(t0) reads complete

    STAGE(4, 0);                         // w2
    {
        float Ac[4][8];
        const float* cr = curr + (size_t)(tok0 + rowl) * DH;
#pragma unroll
        for (int ks = 0; ks < 4; ++ks) {
            float4 a0 = *(const float4*)(cr + ks * 32 + 8 * qd);
            float4 a1 = *(const float4*)(cr + ks * 32 + 8 * qd + 4);
            Ac[ks][0] = a0.x * am_r; Ac[ks][1] = a0.y * am_r;
            Ac[ks][2] = a0.z * am_r; Ac[ks][3] = a0.w * am_r;
            Ac[ks][4] = a1.x * am_r; Ac[ks][5] = a1.y * am_r;
            Ac[ks][6] = a1.z * am_r; Ac[ks][7] = a1.w * am_r;
        }
        Afrag FC; splitA(Ac, FC);
        GEMM(3, FC, 1, acc1);
    }
    // h = relu(acc1 + b1) -> TS (t0 dead; own rows/cols only)
#pragma unroll
    for (int tl = 0; tl < 4; ++tl)
#pragma unroll
        for (int rr = 0; rr < 4; ++rr) {
            const int col = 16 * (4 * colh + tl) + c;
            TS[hr + rr][col] = f2h(fmaxf(acc1[tl][rr] + b1S[col], 0.0f));
        }
    __syncthreads();                     // buf0(w2) ready, h visible

    {
        float Ac[4][8];
#pragma unroll
        for (int ks = 0; ks < 4; ++ks)
#pragma unroll
            for (int j = 0; j < 8; ++j)
                Ac[ks][j] = h2f(TS[rowl][ks * 32 + 8 * qd + j]);
        Afrag FC; splitA(Ac, FC);
        f32x4 acc2[4] = {};
        GEMM(4, FC, 0, acc2);
        __syncthreads();                 // all h reads done before synth overwrite
#pragma unroll
        for (int tl = 0; tl < 4; ++tl)
#pragma unroll
            for (int rr = 0; rr < 4; ++rr) {
                const int col = 16 * (4 * colh + tl) + c;
                TS[hr + rr][col] = f2h(acc2[tl][rr] + b2S[col]);
            }
    }
    __syncthreads();                     // synth visible

    // ---- gate, update, norm, active: 8 threads/token, 16 elems each ----
    const int tok = tid >> 3, d0 = (tid & 7) * 16;
    const float am = actS[tok];
    const float* cp = curr + (size_t)(tok0 + tok) * DH + d0;
    float cv[16];
#pragma unroll
    for (int t = 0; t < 4; ++t) {
        float4 vv = *(const float4*)(cp + t * 4);
        cv[t * 4] = vv.x; cv[t * 4 + 1] = vv.y; cv[t * 4 + 2] = vv.z; cv[t * 4 + 3] = vv.w;
    }
    float srow[16];
#pragma unroll
    for (int e = 0; e < 16; ++e) srow[e] = h2f(TS[tok][d0 + e]);
    float gp = 0.0f;
#pragma unroll
    for (int e = 0; e < 16; ++e)
        gp += cv[e] * am * gwS[d0 + e] + srow[e] * gwS[128 + d0 + e];
    gp += __shfl_xor(gp, 1, 8);
    gp += __shfl_xor(gp, 2, 8);
    gp += __shfl_xor(gp, 4, 8);
    const float gate = 1.0f / (1.0f + __expf(-(gp + gbf)));
    float ss = 0.0f; float up[16];
#pragma unroll
    for (int e = 0; e < 16; ++e) {
        float u = gate * (srow[e] - cv[e] * am) * 0.1f;
        up[e] = u; ss += u * u;
    }
    ss += __shfl_xor(ss, 1, 8);
    ss += __shfl_xor(ss, 2, 8);
    ss += __shfl_xor(ss, 4, 8);
    const bool stable = sqrtf(ss) < 0.1f;

    if (last) {
        size_t off = (size_t)(tok0 + tok) * DH + d0;
        if (isb) {
            __hip_bfloat16* op = (__hip_bfloat16*)dout + off;
#pragma unroll
            for (int e = 0; e < 16; ++e) op[e] = __float2bfloat16(cv[e] + up[e]);
        } else {
            float* op = (float*)dout + off;
#pragma unroll
            for (int t = 0; t < 4; ++t)
                *(float4*)(op + t * 4) = make_float4(cv[t * 4] + up[t * 4], cv[t * 4 + 1] + up[t * 4 + 1],
                                                     cv[t * 4 + 2] + up[t * 4 + 2], cv[t * 4 + 3] + up[t * 4 + 3]);
        }
    } else {
        float* op = cur_out + (size_t)(tok0 + tok) * DH + d0;
#pragma unroll
        for (int t = 0; t < 4; ++t)
            *(float4*)(op + t * 4) = make_float4(cv[t * 4] + up[t * 4], cv[t * 4 + 1] + up[t * 4 + 1],
                                                 cv[t * 4 + 2] + up[t * 4 + 2], cv[t * 4 + 3] + up[t * 4 + 3]);
    }
    const int newact = (am > 0.0f && !stable) ? 1 : 0;
    if ((tid & 7) == 0) {
        active[tok0 + tok] = newact;
        if (newact) atomicAdd(&blkcnt, 1);
    }
    __syncthreads();
    if (tid == 0 && blkcnt > 0) atomicAdd(&counts[r + 1], blkcnt);
}

extern "C" void kernel_launch(void* const* d_in, const int* in_sizes, int n_in,
                              void* d_out, int out_size, void* d_ws, size_t ws_size,
                              hipStream_t stream) {
    const void* x  = d_in[0];
    const void* wq = d_in[1];
    const void* wk = d_in[2];
    const void* wv = d_in[3];
    const void* tw = d_in[4];
    const void* tb = d_in[5];
    const void* ab = d_in[6];
    const void* w1 = d_in[7];
    const void* b1 = d_in[8];
    const void* w2 = d_in[9];
    const void* b2 = d_in[10];
    const void* gw = d_in[11];
    const void* gb = d_in[12];

    u32* ws = (u32*)d_ws;
    const size_t N1 = (size_t)BS_ * DH;
    // base layout (~24 MiB): qp | kp | vp | active | counts | flag
    u32* qp = ws;
    u32* kp = ws + N1;        // K MFMA-frags (4 MB used of 8 MB region)
    u32* vp = ws + 2 * N1;    // V MFMA-frags (4 MB used of 8 MB region)
    int* active = (int*)(ws + 3 * N1);
    int* counts = active + BS_;
    int* flag   = counts + 4;
    float* cur0  = (float*)qp;    // small-ws path only
    float* cur_r = (float*)kp;    // overwrites dead K-frags after attn
    // split-KV x4 extension (f16 partials), ends at 42.2 MB <= 42.3 MB guarantee
    u16* Opart16 = (u16*)(ws + 3 * N1 + 32768);
    u16* lpart16 = (u16*)(ws + 5 * N1 + 32768);
    const bool big_ws = ws_size >= (size_t)42300000;        // constant across calls
    // prepacked QKV W: transient in Opart region (dead before attention writes it)
    u32x4* wpk = (u32x4*)(ws + 3 * N1 + 32768);
    // vp region after attention (V-frags dead): pkRW at base (320 KB), T0 cache at +512 KB (4 MB)
    u32x4* pkRW = (u32x4*)vp;
    u16*   T0c  = (u16*)(vp + 131072);
    u32x4* kfragP = (u32x4*)kp;
    u32x4* vfragP = (u32x4*)vp;

    init_kernel<<<dim3(BS_ / 256), 256, 0, stream>>>(x, flag, active, counts);
    prepack_w_kernel<<<dim3(192), 256, 0, stream>>>(wq, wk, wv, flag, wpk);
    qkv_kernel<<<dim3(BS_ / 64, 1, 3), 256, 0, stream>>>(x, wpk, flag, qp, kfragP, vfragP);
    if (big_ws) {
        attn_split_kernel<<<dim3(S_ / 64, B_, 4), 256, 0, stream>>>(qp, kfragP, vfragP, Opart16, lpart16);
    } else {
        attn_kernel<<<dim3(S_ / 64, B_), 256, 0, stream>>>(qp, kfragP, vfragP, cur0);
    }
    prepack_rw_kernel<<<dim3(40), 256, 0, stream>>>(tw, w1, w2, flag, pkRW);
    // round 0: fused combine + round math + T0 cache
    round0_kernel<<<dim3(BS_ / 16), 256, 0, stream>>>(
        cur0, Opart16, lpart16, pkRW, T0c, tb, ab, b1, b2, gw, gb,
        flag, active, counts, cur_r, big_ws ? 1 : 0);
    round_kernel<<<dim3(BS_ / 32), 256, 0, stream>>>(
        cur_r, pkRW, T0c, tb, ab, b1, b2, gw, gb, flag, active, counts, 1, cur_r, nullptr);
    round_kernel<<<dim3(BS_ / 32), 256, 0, stream>>>(
        cur_r, pkRW, T0c, tb, ab, b1, b2, gw, gb, flag, active, counts, 2, cur_r, d_out);
}

// Round 20
// 249.654 us; speedup vs baseline: 1.1508x; 1.0150x over previous
//
#include <hip/hip_runtime.h>
#include <hip/hip_bf16.h>

#define B_   8
#define S_   2048
#define DM   1024
#define DH   128
#define BS_  16384
#define SCALE_  0.08838834764831845f
#define SCALE2_ 0.12751744f   // SCALE * log2(e)

typedef unsigned short u16;
typedef unsigned int   u32;
typedef _Float16 half8 __attribute__((ext_vector_type(8)));
typedef __bf16   bf16x8 __attribute__((ext_vector_type(8)));
typedef float    f32x4 __attribute__((ext_vector_type(4)));
typedef u32      u32x4 __attribute__((ext_vector_type(4)));

union H8 { u32x4 v; u32 u[4]; half8 h; bf16x8 b; };

__device__ __forceinline__ float bf2f(u16 u) {
    union { u32 i; float f; } w; w.i = ((u32)u) << 16; return w.f;
}
__device__ __forceinline__ void unpack8(uint4 v, float* f) {
    f[0] = bf2f(v.x & 0xffff); f[1] = bf2f(v.x >> 16);
    f[2] = bf2f(v.y & 0xffff); f[3] = bf2f(v.y >> 16);
    f[4] = bf2f(v.z & 0xffff); f[5] = bf2f(v.z >> 16);
    f[6] = bf2f(v.w & 0xffff); f[7] = bf2f(v.w >> 16);
}
__device__ __forceinline__ float ldE(const void* b, size_t i, int isbf16) {
    return isbf16 ? bf2f(((const u16*)b)[i]) : ((const float*)b)[i];
}
__device__ __forceinline__ void ld8(const void* b, size_t i, int isbf16, float* f) {
    if (isbf16) {
        unpack8(*(const uint4*)((const u16*)b + i), f);
    } else {
        float4 a = *(const float4*)((const float*)b + i);
        float4 c = *(const float4*)((const float*)b + i + 4);
        f[0] = a.x; f[1] = a.y; f[2] = a.z; f[3] = a.w;
        f[4] = c.x; f[5] = c.y; f[6] = c.z; f[7] = c.w;
    }
}
// fp32 -> packed (f16 hi << 16) | f16 lo  (2-term split, ~22 mantissa bits)
__device__ __forceinline__ u32 f2pk(float v) {
    _Float16 h = (_Float16)v;
    _Float16 l = (_Float16)(v - (float)h);
    union { _Float16 f; u16 u; } a, b; a.f = h; b.f = l;
    return ((u32)a.u << 16) | (u32)b.u;
}
// 8 floats -> pair-packed hi/lo frag u32x4
__device__ __forceinline__ void split8(const float* f, u32x4& hi, u32x4& lo) {
    u32 H[8], L[8];
#pragma unroll
    for (int j = 0; j < 8; ++j) {
        _Float16 h = (_Float16)f[j];
        _Float16 l = (_Float16)(f[j] - (float)h);
        union { _Float16 x; u16 u; } a, b; a.x = h; b.x = l;
        H[j] = a.u; L[j] = b.u;
    }
    hi = (u32x4){H[0] | (H[1] << 16), H[2] | (H[3] << 16), H[4] | (H[5] << 16), H[6] | (H[7] << 16)};
    lo = (u32x4){L[0] | (L[1] << 16), L[2] | (L[3] << 16), L[4] | (L[5] << 16), L[6] | (L[7] << 16)};
}
__device__ __forceinline__ u32 permHI(u32 eB, u32 eA) { return __builtin_amdgcn_perm(eB, eA, 0x07060302u); }
__device__ __forceinline__ u16 f2h(float v) { union { _Float16 f; u16 u; } a; a.f = (_Float16)v; return a.u; }
__device__ __forceinline__ float h2f(u16 u) { union { _Float16 f; u16 u; } a; a.u = u; return (float)a.f; }

// ---------------- init: dtype detect + active mask + round counters ----------------
__global__ void init_kernel(const void* x, int* flag, int* active, int* counts) {
    int i = blockIdx.x * 256 + threadIdx.x;
    if (i < BS_) active[i] = 1;
    if (i < 4) counts[i] = (i == 0) ? BS_ : 0;
    if (i == 0) {
        const u16* w = (const u16*)x;
        int sane = 0;
        for (int t = 0; t < 256; ++t) {
            int e = (w[2 * t] >> 7) & 0xFF;
            if (e >= 100 && e <= 135) ++sane;
        }
        *flag = (sane >= 192) ? 1 : 0;   // 1 = bf16, 0 = fp32
    }
}

// ---------------- prepack W into MFMA fragment layout ----------------
// bf16 path: hi slot = raw bf16 pairs (lo unused). fp32 path: f16 hi/lo split.
__global__ __launch_bounds__(256) void prepack_w_kernel(
    const void* __restrict__ wq, const void* __restrict__ wk, const void* __restrict__ wv,
    const int* __restrict__ flag, u32x4* __restrict__ wpk)
{
    const int isb = *flag;
    const int gid = blockIdx.x * 256 + threadIdx.x;
    const int l  = gid & 63;
    const int t  = (gid >> 6) & 7;
    const int ks = (gid >> 9) & 31;
    const int z  = gid >> 14;
    const void* W = (z == 0) ? wq : (z == 1) ? wk : wv;
    const int row = 16 * t + (l & 15);
    const int k0  = ks * 32 + 8 * (l >> 4);
    const size_t base = ((((size_t)z * 32 + ks) * 16) + 2 * t) * 64 + l;
    if (isb) {
        uint4 v = *(const uint4*)((const u16*)W + (size_t)row * DM + k0);
        wpk[base] = (u32x4){v.x, v.y, v.z, v.w};
    } else {
        float f[8];
        ld8(W, (size_t)row * DM + k0, 0, f);
        u32x4 hi, lo;
        split8(f, hi, lo);
        wpk[base]      = hi;
        wpk[base + 64] = lo;
    }
}

// ---------------- MFMA QKV (R11 form): 64 rows/block, BK=64 staged, grid (256,1,3) ----------------
// z=0: Q as raw f16 (u16[row][dh]; attention consumes hi-plane only, bit-identical).
// z=1: K MFMA-frags. z=2: V MFMA-frags.
__global__ __launch_bounds__(256) void qkv_kernel(
    const void* __restrict__ x, const u32x4* __restrict__ wpk,
    const int* __restrict__ flag, u16* __restrict__ qout,
    u32x4* __restrict__ kfrag, u32x4* __restrict__ vfrag)
{
    const int isb = *flag;
    const int z = blockIdx.z;
    // XCD swizzle (bijective on [0,256)): consecutive x-tiles stay on one XCD
    const int bx = blockIdx.x;
    const int m0 = ((bx & 7) * 32 + (bx >> 3)) * 64;
    const int tid = threadIdx.x;
    const int wave = tid >> 6, lane = tid & 63;
    const int qd = lane >> 4, c = lane & 15;

    __shared__ u32x4 WLraw[2][16][64];   // 32 KB; TS overlays after the loop
    // views
    u32x4 (*WLb)[2][8][64] = (u32x4(*)[2][8][64])WLraw;   // bf16: [buf][ksub][t][lane]
    u32x4 (*WLf)[8][2][64] = (u32x4(*)[8][2][64])WLraw;   // fp32: [buf][t][plane][lane]
    u16 (*TS)[136] = (u16(*)[136])WLraw;                  // 17.4 KB overlay

    const u32x4* wz = wpk + (size_t)z * (32 * 16 * 64);
    const size_t arow = (size_t)(m0 + wave * 16 + c) * DM + 8 * qd;

// bf16 BK=64 stage: iter i covers ks=2i,2i+1; 16 hi slabs, 4 per wave
#define STAGE2(i_, b_)                                                            \
    {                                                                             \
        _Pragma("unroll")                                                         \
        for (int _j = 0; _j < 4; ++_j) {                                          \
            const int _g = wave * 4 + _j, _ksub = _g >> 3, _t = _g & 7;           \
            __builtin_amdgcn_global_load_lds(                                     \
                (const __attribute__((address_space(1))) u32*)(                   \
                    wz + ((size_t)(2 * (i_) + _ksub) * 16 + 2 * _t) * 64 + lane), \
                (__attribute__((address_space(3))) u32*)&WLb[b_][_ksub][_t][0],   \
                16, 0, 0);                                                        \
        }                                                                         \
    }
// fp32 stage (1 K-step): 16 slabs (8 tiles x hi/lo), 4 per wave
#define STAGE_W(ks_, b_)                                                          \
    {                                                                             \
        const u32x4* _src = wz + ((size_t)(ks_) * 16 + 4 * wave) * 64 + lane;     \
        _Pragma("unroll")                                                         \
        for (int _j = 0; _j < 4; ++_j) {                                          \
            __builtin_amdgcn_global_load_lds(                                     \
                (const __attribute__((address_space(1))) u32*)(_src + _j * 64),   \
                (__attribute__((address_space(3))) u32*)&WLf[b_][2 * wave + (_j >> 1)][_j & 1][0], \
                16, 0, 0);                                                        \
        }                                                                         \
    }

    f32x4 acc[8] = {};

    if (isb) {
        const u16* xb = (const u16*)x;
        uint4 A0 = *(const uint4*)(xb + arow);
        uint4 A1 = *(const uint4*)(xb + arow + 32);
        STAGE2(0, 0);
        uint4 A0n = *(const uint4*)(xb + arow + 64);
        uint4 A1n = *(const uint4*)(xb + arow + 96);
        __syncthreads();
        for (int i = 0; i < 16; ++i) {
            const int cb = i & 1;
            if (i + 1 < 16) STAGE2(i + 1, cb ^ 1);
            H8 Ah0; Ah0.v = (u32x4){A0.x, A0.y, A0.z, A0.w};
            H8 Ah1; Ah1.v = (u32x4){A1.x, A1.y, A1.z, A1.w};
#pragma unroll
            for (int t = 0; t < 8; ++t) {
                H8 bh; bh.v = WLb[cb][0][t][lane];
                acc[t] = __builtin_amdgcn_mfma_f32_16x16x32_bf16(Ah0.b, bh.b, acc[t], 0, 0, 0);
            }
#pragma unroll
            for (int t = 0; t < 8; ++t) {
                H8 bh; bh.v = WLb[cb][1][t][lane];
                acc[t] = __builtin_amdgcn_mfma_f32_16x16x32_bf16(Ah1.b, bh.b, acc[t], 0, 0, 0);
            }
            A0 = A0n; A1 = A1n;
            if (i + 2 < 16) {
                A0n = *(const uint4*)(xb + arow + (size_t)(i + 2) * 64);
                A1n = *(const uint4*)(xb + arow + (size_t)(i + 2) * 64 + 32);
            }
            __syncthreads();
        }
    } else {
        float Ar[8], Arn[8];
        ld8(x, arow, 0, Ar);
        STAGE_W(0, 0);
        ld8(x, arow + 32, 0, Arn);
        __syncthreads();
        for (int ks = 0; ks < 32; ++ks) {
            const int cb = ks & 1;
            if (ks + 1 < 32) STAGE_W(ks + 1, cb ^ 1);
            H8 Ah, Al;
            split8(Ar, Ah.v, Al.v);
#pragma unroll
            for (int t = 0; t < 8; ++t) {
                H8 bh, bl;
                bh.v = WLf[cb][t][0][lane]; bl.v = WLf[cb][t][1][lane];
                acc[t] = __builtin_amdgcn_mfma_f32_16x16x32_f16(Al.h, bh.h, acc[t], 0, 0, 0);
                acc[t] = __builtin_amdgcn_mfma_f32_16x16x32_f16(Ah.h, bl.h, acc[t], 0, 0, 0);
                acc[t] = __builtin_amdgcn_mfma_f32_16x16x32_f16(Ah.h, bh.h, acc[t], 0, 0, 0);
            }
#pragma unroll
            for (int j = 0; j < 8; ++j) Ar[j] = Arn[j];
            if (ks + 2 < 32) ld8(x, arow + (size_t)(ks + 2) * 32, 0, Arn);
            __syncthreads();
        }
    }
#undef STAGE2
#undef STAGE_W

    if (z == 0) {
#pragma unroll
        for (int r = 0; r < 4; ++r) {
            const int row = m0 + wave * 16 + qd * 4 + r;
            u16* op = qout + (size_t)row * DH + c;
#pragma unroll
            for (int t = 0; t < 8; ++t) op[t * 16] = f2h(acc[t][r]);
        }
    } else {
        // stage [key(local)][dh] f16 tile (overlays WL; loop's final barrier protects)
#pragma unroll
        for (int t = 0; t < 8; ++t)
#pragma unroll
            for (int r = 0; r < 4; ++r)
                TS[wave * 16 + qd * 4 + r][16 * t + c] = f2h(acc[t][r]);
        __syncthreads();
        if (z == 1) {
            // kfrag[kt16][ks][lane] = K[kt16*16 + (lane&15)][ks*32 + 8*(lane>>4) + j]
#pragma unroll
            for (int i = 0; i < 4; ++i) {
                const int f = tid + 256 * i;          // 0..1023
                const int lf = f & 63, ks = (f >> 6) & 3, sub = f >> 8;
                const int key = sub * 16 + (lf & 15);
                const int d0  = ks * 32 + 8 * (lf >> 4);
                u32 w[4];
#pragma unroll
                for (int q = 0; q < 4; ++q)
                    w[q] = (u32)TS[key][d0 + 2 * q] | ((u32)TS[key][d0 + 2 * q + 1] << 16);
                kfrag[((size_t)(m0 / 16 + sub) * 4 + ks) * 64 + lf] = (u32x4){w[0], w[1], w[2], w[3]};
            }
        } else {
            // vfrag[kt32][t][lane] = V[kt32*32 + 8*(lane>>4) + j][16t + (lane&15)]
#pragma unroll
            for (int i = 0; i < 4; ++i) {
                const int f = tid + 256 * i;          // 0..1023
                const int lf = f & 63, t = (f >> 6) & 7, sub = f >> 9;
                const int kb2 = sub * 32 + 8 * (lf >> 4);
                const int dh  = 16 * t + (lf & 15);
                u32 w[4];
#pragma unroll
                for (int q = 0; q < 4; ++q)
                    w[q] = (u32)TS[kb2 + 2 * q][dh] | ((u32)TS[kb2 + 2 * q + 1][dh] << 16);
                vfrag[((size_t)(m0 / 32 + sub) * 8 + t) * 64 + lf] = (u32x4){w[0], w[1], w[2], w[3]};
            }
        }
    }
}

// ---------------- attention core: barrier-free, frags from global (L2-hot) ----------------
// Q stored as raw f16: u32 view of q16[d] = (f16(d) | f16(d+1)<<16) == old permHI result.
// PB stride 40 u16 (80 B): rows 16B-aligned -> P re-read is one ds_read_b128, conflict-free.
template <bool WRITE_PARTIAL>
__device__ __forceinline__ void attn_body(
    const u16* qp, const u32x4* __restrict__ kfrag, const u32x4* __restrict__ vfrag,
    u16* outO, u16* outL, float* cur,
    int b, int q0, int kt0, int kt1, int part)
{
    const int tid = threadIdx.x;
    const int wave = tid >> 6, lane = tid & 63;
    const int qd = lane >> 4, c = lane & 15;

    __shared__ __align__(16) u16 PB[4][640];   // per-wave P, stride 40 (wave-private)

    H8 Qh[4];
    {
        const u16* qr = qp + ((size_t)b * S_ + q0 + wave * 16 + c) * DH;
#pragma unroll
        for (int ks = 0; ks < 4; ++ks) {
            uint4 e0 = *(const uint4*)(qr + ks * 32 + qd * 8);
            Qh[ks].u[0] = e0.x; Qh[ks].u[1] = e0.y;
            Qh[ks].u[2] = e0.z; Qh[ks].u[3] = e0.w;
        }
    }

    f32x4 O[8] = {};
    float lsum[4] = {};

    const u32x4* kb0 = kfrag + (size_t)b * 128 * 256;   // kt16 stride = 4*64
    const u32x4* vb0 = vfrag + (size_t)b * 64 * 512;    // kt32 stride = 8*64

    for (int kt = kt0; kt < kt1; ++kt) {
        const u32x4* kf = kb0 + (size_t)kt * 512;       // two kt16 blocks
        const u32x4* vf = vb0 + (size_t)kt * 512;

        f32x4 S0 = {}, S1 = {};
        __builtin_amdgcn_s_setprio(1);
#pragma unroll
        for (int ks = 0; ks < 4; ++ks) {
            H8 kh;
            kh.v = kf[ks * 64 + lane];
            S0 = __builtin_amdgcn_mfma_f32_16x16x32_f16(Qh[ks].h, kh.h, S0, 0, 0, 0);
            kh.v = kf[256 + ks * 64 + lane];
            S1 = __builtin_amdgcn_mfma_f32_16x16x32_f16(Qh[ks].h, kh.h, S1, 0, 0, 0);
        }
        __builtin_amdgcn_s_setprio(0);

        u16* pw = PB[wave];
#pragma unroll
        for (int r = 0; r < 4; ++r) {
            float e0 = exp2f(fmaf(S0[r], SCALE2_, -4.0f));
            float e1 = exp2f(fmaf(S1[r], SCALE2_, -4.0f));
            lsum[r] += e0 + e1;
            pw[(4 * qd + r) * 40 + c]      = f2h(e0);
            pw[(4 * qd + r) * 40 + 16 + c] = f2h(e1);
        }

        uint4 ev = *(const uint4*)&pw[c * 40 + 8 * qd];   // one b128: P row c, keys 8qd..8qd+7
        H8 Ph;
        Ph.u[0] = ev.x; Ph.u[1] = ev.y; Ph.u[2] = ev.z; Ph.u[3] = ev.w;

        __builtin_amdgcn_s_setprio(1);
#pragma unroll
        for (int t = 0; t < 8; ++t) {
            H8 vh;
            vh.v = vf[t * 64 + lane];
            O[t] = __builtin_amdgcn_mfma_f32_16x16x32_f16(Ph.h, vh.h, O[t], 0, 0, 0);
        }
        __builtin_amdgcn_s_setprio(0);
    }

    if (WRITE_PARTIAL) {
        float lred[4];
#pragma unroll
        for (int r = 0; r < 4; ++r) {
            float l = lsum[r];
            l += __shfl_xor(l, 1); l += __shfl_xor(l, 2);
            l += __shfl_xor(l, 4); l += __shfl_xor(l, 8);
            lred[r] = l;
        }
        const size_t rb = (size_t)b * S_ + q0 + wave * 16 + 4 * qd;
        u16* Op = outO + (size_t)part * ((size_t)BS_ * DH);
#pragma unroll
        for (int t = 0; t < 8; ++t)
#pragma unroll
            for (int r = 0; r < 4; ++r)
                Op[(rb + r) * DH + t * 16 + c] = f2h(O[t][r]);
        if (c == 0) {
            u16* lp = outL + (size_t)part * BS_;
#pragma unroll
            for (int r = 0; r < 4; ++r) lp[rb + r] = f2h(lred[r]);
        }
    } else {
        float linv[4];
#pragma unroll
        for (int r = 0; r < 4; ++r) {
            float l = lsum[r];
            l += __shfl_xor(l, 1); l += __shfl_xor(l, 2);
            l += __shfl_xor(l, 4); l += __shfl_xor(l, 8);
            linv[r] = 1.0f / l;
        }
        const size_t rb = (size_t)b * S_ + q0 + wave * 16 + 4 * qd;
#pragma unroll
        for (int t = 0; t < 8; ++t)
#pragma unroll
            for (int r = 0; r < 4; ++r)
                cur[(rb + r) * DH + t * 16 + c] = O[t][r] * linv[r];
    }
}

// single-pass fallback: grid (32, 8). XCD swizzle: batch = rid&7 (bijective).
__global__ __launch_bounds__(256) void attn_kernel(
    const u16* qp, const u32x4* __restrict__ kfrag, const u32x4* __restrict__ vfrag, float* cur)
{
    const int rid = blockIdx.x + 32 * blockIdx.y;
    attn_body<false>(qp, kfrag, vfrag, nullptr, nullptr, cur,
                     rid & 7, ((rid >> 3) & 31) * 64, 0, S_ / 32, 0);
}

// split-KV x4: grid (32, 8, 4) = 1024 blocks. batch = rid&7 per XCD.
__global__ __launch_bounds__(256) void attn_split_kernel(
    const u16* qp, const u32x4* __restrict__ kfrag, const u32x4* __restrict__ vfrag,
    u16* __restrict__ Opart, u16* __restrict__ lpart)
{
    const int rid = blockIdx.x + 32 * (blockIdx.y + 8 * blockIdx.z);
    const int b    = rid & 7;
    const int qx   = (rid >> 3) & 31;
    const int part = rid >> 8;
    const int quart = S_ / 128;   // 16 tiles per part
    attn_body<true>(qp, kfrag, vfrag, Opart, lpart, nullptr,
                    b, qx * 64, part * quart, (part + 1) * quart, part);
}

// ---------------- prepack round weights (straight repack, no algebra) ----------------
// mats: 0=tw, 1=w1[:,0:128], 2=w1[:,128:256], 3=w1[:,256:384], 4=w2
__global__ __launch_bounds__(256) void prepack_rw_kernel(
    const void* __restrict__ tw, const void* __restrict__ w1, const void* __restrict__ w2,
    const int* __restrict__ flag, u32x4* __restrict__ pk)
{
    const int isb = *flag;
    const int gid = blockIdx.x * 256 + threadIdx.x;   // 10240 total
    const int l = gid & 63, t = (gid >> 6) & 7, ks = (gid >> 9) & 3, mat = gid >> 11;
    const int row = 16 * t + (l & 15);
    const int k0  = ks * 32 + 8 * (l >> 4);
    float f[8];
    if (mat == 0)      ld8(tw, (size_t)row * DH + k0, isb, f);
    else if (mat <= 3) ld8(w1, (size_t)row * 384 + (mat - 1) * 128 + k0, isb, f);
    else               ld8(w2, (size_t)row * DH + k0, isb, f);
    u32x4 hi, lo;
    split8(f, hi, lo);
    const size_t base = (((size_t)mat * 4 + ks) * 16 + 2 * t) * 64 + l;
    pk[base] = hi; pk[base + 64] = lo;
}

// pre-split A fragments
struct Afrag { H8 h[4], l[4]; };
__device__ __forceinline__ void splitA(const float (&A)[4][8], Afrag& F) {
#pragma unroll
    for (int ks = 0; ks < 4; ++ks) split8(A[ks], F.h[ks].v, F.l[ks].v);
}

// ---------------- round 0: fused combine + dialectic round, 16 tokens/block, grid 1024 ----------
// Builds combined cur0 in LDS (CS, f32, bit-identical to old combine_kernel output),
// runs round-0 math (all tokens active, am=1), caches t0 to T0 for rounds 1-2.
__global__ __launch_bounds__(256) void round0_kernel(
    const float* __restrict__ cur0g,
    const u16* __restrict__ Opart, const u16* __restrict__ lpart,
    const u32x4* __restrict__ pk, u16* __restrict__ T0,
    const void* __restrict__ tb, const void* __restrict__ ab,
    const void* __restrict__ b1, const void* __restrict__ b2,
    const void* __restrict__ gw, const void* __restrict__ gb,
    const int* __restrict__ flag, int* active, int* counts,
    float* cur_out, int combine)
{
    const int isb = *flag;
    const int tok0 = blockIdx.x * 16;
    const int tid = threadIdx.x;
    const int wave = tid >> 6, lane = tid & 63;
    const int qd = lane >> 4, c = lane & 15;

    __shared__ u32x4 WB[2][2][8][64];   // 32 KB: [buf][kl(or plane)][t][lane]
    __shared__ u16 TS[16][132];         // t0 -> h -> synth (f16)
    __shared__ float CS[16][128];       // combined cur0 rows (f32, 8 KB)
    __shared__ float tbS[128], abS[128], b1S[128], b2S[128], gwS[256];
    __shared__ int blkcnt;

    auto stageBh = [&](int mat, int h) {
#pragma unroll
        for (int j = 0; j < 4; ++j) {
            const int g = wave * 4 + j, kl = g >> 3, t = g & 7;
            __builtin_amdgcn_global_load_lds(
                (const __attribute__((address_space(1))) u32*)(
                    pk + (((size_t)mat * 4 + 2 * h + kl) * 16 + 2 * t) * 64 + lane),
                (__attribute__((address_space(3))) u32*)&WB[h][kl][t][0],
                16, 0, 0);
        }
    };
    auto gemmBh = [&](const Afrag& F, int h, f32x4 (&acc)[2]) {
#pragma unroll
        for (int kl = 0; kl < 2; ++kl) {
            const int ks = 2 * h + kl;
#pragma unroll
            for (int tl = 0; tl < 2; ++tl) {
                H8 bh; bh.v = WB[h][kl][2 * wave + tl][lane];
                acc[tl] = __builtin_amdgcn_mfma_f32_16x16x32_f16(F.l[ks].h, bh.h, acc[tl], 0, 0, 0);
                acc[tl] = __builtin_amdgcn_mfma_f32_16x16x32_f16(F.h[ks].h, bh.h, acc[tl], 0, 0, 0);
            }
        }
    };
    auto stageFq = [&](int mat, int q, int buf) {
#pragma unroll
        for (int j = 0; j < 4; ++j) {
            const int g = wave * 4 + j, p = g & 1, t = g >> 1;
            __builtin_amdgcn_global_load_lds(
                (const __attribute__((address_space(1))) u32*)(
                    pk + (((size_t)mat * 4 + q) * 16 + 2 * t + p) * 64 + lane),
                (__attribute__((address_space(3))) u32*)&WB[buf][p][t][0],
                16, 0, 0);
        }
    };
    auto gemmFq = [&](const Afrag& F, int q, int buf, f32x4 (&acc)[2]) {
#pragma unroll
        for (int tl = 0; tl < 2; ++tl) {
            H8 bh, bl;
            bh.v = WB[buf][0][2 * wave + tl][lane];
            bl.v = WB[buf][1][2 * wave + tl][lane];
            acc[tl] = __builtin_amdgcn_mfma_f32_16x16x32_f16(F.l[q].h, bh.h, acc[tl], 0, 0, 0);
            acc[tl] = __builtin_amdgcn_mfma_f32_16x16x32_f16(F.h[q].h, bl.h, acc[tl], 0, 0, 0);
            acc[tl] = __builtin_amdgcn_mfma_f32_16x16x32_f16(F.h[q].h, bh.h, acc[tl], 0, 0, 0);
        }
    };
    auto GEMMF = [&](int mat, const Afrag& F, f32x4 (&acc)[2]) {
        for (int q = 0; q < 4; ++q) {
            stageFq(mat, q, q & 1);
            __syncthreads();
            gemmFq(F, q, q & 1, acc);
            __syncthreads();
        }
    };

    const int hr = 4 * qd;
    const int rowl = c;

    auto writeTS = [&](const f32x4 (&acc)[2], const float* bias, bool relu) {
#pragma unroll
        for (int tl = 0; tl < 2; ++tl)
#pragma unroll
            for (int rr = 0; rr < 4; ++rr) {
                const int col = 16 * (2 * wave + tl) + c;
                float v = acc[tl][rr] + (bias ? bias[col] : 0.0f);
                TS[hr + rr][col] = f2h(relu ? fmaxf(v, 0.0f) : v);
            }
    };
    auto buildA1 = [&](Afrag& F) {
        float Ac[4][8];
#pragma unroll
        for (int ks = 0; ks < 4; ++ks)
#pragma unroll
            for (int j = 0; j < 8; ++j)
                Ac[ks][j] = CS[rowl][ks * 32 + 8 * qd + j];
        splitA(Ac, F);
    };
    auto buildAt = [&](Afrag& F) {
        float Ac[4][8];
#pragma unroll
        for (int ks = 0; ks < 4; ++ks)
#pragma unroll
            for (int j = 0; j < 8; ++j) {
                const int k = ks * 32 + 8 * qd + j;
                Ac[ks][j] = h2f(TS[rowl][k]) + tbS[k];
            }
        splitA(Ac, F);
    };
    auto buildAa = [&](Afrag& F) {
        float Ac[4][8];
#pragma unroll
        for (int ks = 0; ks < 4; ++ks)
#pragma unroll
            for (int j = 0; j < 8; ++j) {
                const int k = ks * 32 + 8 * qd + j;
                Ac[ks][j] = abS[k] - h2f(TS[rowl][k]);
            }
        splitA(Ac, F);
    };
    auto buildAh = [&](Afrag& F) {
        float Ac[4][8];
#pragma unroll
        for (int ks = 0; ks < 4; ++ks)
#pragma unroll
            for (int j = 0; j < 8; ++j)
                Ac[ks][j] = h2f(TS[rowl][ks * 32 + 8 * qd + j]);
        splitA(Ac, F);
    };

    // ---- constants + combined cur0 into CS (8 elems/thread) ----
    if (tid < 128) {
        tbS[tid] = ldE(tb, tid, isb); abS[tid] = ldE(ab, tid, isb);
        b1S[tid] = ldE(b1, tid, isb); b2S[tid] = ldE(b2, tid, isb);
    }
    gwS[tid] = ldE(gw, tid, isb);
    if (tid == 0) blkcnt = 0;
    const float gbf = ldE(gb, 0, isb);
    {
        const int row = tid >> 4, d0 = (tid & 15) * 8;
        float a8[8];
        if (combine) {
            const size_t grow = (size_t)(tok0 + row);
            const float lt = h2f(lpart[grow]) + h2f(lpart[BS_ + grow])
                           + h2f(lpart[2 * BS_ + grow]) + h2f(lpart[3 * BS_ + grow]);
            const float linv = 1.0f / lt;
            float acc[8] = {};
            const size_t N1 = (size_t)BS_ * DH;
#pragma unroll
            for (int p = 0; p < 4; ++p) {
                const u16* op = Opart + (size_t)p * N1 + grow * DH + d0;
                uint4 v0 = *(const uint4*)op;
                const u32 w[4] = {v0.x, v0.y, v0.z, v0.w};
#pragma unroll
                for (int j = 0; j < 4; ++j) {
                    acc[2 * j]     += h2f((u16)(w[j] & 0xffff));
                    acc[2 * j + 1] += h2f((u16)(w[j] >> 16));
                }
            }
#pragma unroll
            for (int e = 0; e < 8; ++e) a8[e] = acc[e] * linv;
        } else {
            const float* cr = cur0g + (size_t)(tok0 + row) * DH + d0;
            float4 v0 = *(const float4*)cr;
            float4 v1 = *(const float4*)(cr + 4);
            a8[0] = v0.x; a8[1] = v0.y; a8[2] = v0.z; a8[3] = v0.w;
            a8[4] = v1.x; a8[5] = v1.y; a8[6] = v1.z; a8[7] = v1.w;
        }
#pragma unroll
        for (int e = 0; e < 8; ++e) CS[row][d0 + e] = a8[e];
    }

    if (isb) {
        stageBh(0, 0);
        __syncthreads();                 // WB0(tw.h0) + CS + consts
        Afrag FA; buildA1(FA);
        stageBh(0, 1);
        f32x4 accT[2] = {};
        gemmBh(FA, 0, accT);
        __syncthreads();                 // WB1(tw.h1)
        stageBh(1, 0);
        gemmBh(FA, 1, accT);
        writeTS(accT, nullptr, false);   // t0
        __syncthreads();                 // WB0(w1a.h0) + TS(t0)
        for (int i = tid; i < 16 * 64; i += 256) {
            const int row = i >> 6, c2 = (i & 63) * 2;
            *(u32*)&T0[(size_t)(tok0 + row) * DH + c2] = *(const u32*)&TS[row][c2];
        }
        f32x4 acc1[2] = {};
        {   // at @ w1a
            Afrag FC; buildAt(FC);
            stageBh(1, 1);
            gemmBh(FC, 0, acc1);
            __syncthreads();             // WB1(w1a.h1)
            stageBh(2, 0);
            gemmBh(FC, 1, acc1);
            __syncthreads();             // WB0(w1b.h0)
        }
        {   // aa @ w1b
            Afrag FC; buildAa(FC);
            stageBh(2, 1);
            gemmBh(FC, 0, acc1);
            __syncthreads();             // WB1(w1b.h1)
            stageBh(3, 0);
            gemmBh(FC, 1, acc1);
            __syncthreads();             // WB0(w1c.h0)
        }
        {   // ac @ w1c (A = CS rows, am = 1)
            Afrag FC; buildA1(FC);
            stageBh(3, 1);
            gemmBh(FC, 0, acc1);
            __syncthreads();             // WB1(w1c.h1)
            stageBh(4, 0);
            gemmBh(FC, 1, acc1);
        }
        writeTS(acc1, b1S, true);        // h (t0 readers done >=2 barriers ago)
        __syncthreads();                 // WB0(w2.h0) + TS(h)
        {   // h @ w2
            Afrag FC; buildAh(FC);
            stageBh(4, 1);
            f32x4 acc2[2] = {};
            gemmBh(FC, 0, acc2);
            __syncthreads();             // WB1(w2.h1); separates h reads from synth write
            gemmBh(FC, 1, acc2);
            writeTS(acc2, b2S, false);   // synth
        }
        __syncthreads();                 // synth visible
    } else {
        __syncthreads();                 // CS + consts
        Afrag FA; buildA1(FA);
        f32x4 accT[2] = {};
        GEMMF(0, FA, accT);
        writeTS(accT, nullptr, false);
        __syncthreads();
        for (int i = tid; i < 16 * 64; i += 256) {
            const int row = i >> 6, c2 = (i & 63) * 2;
            *(u32*)&T0[(size_t)(tok0 + row) * DH + c2] = *(const u32*)&TS[row][c2];
        }
        f32x4 acc1[2] = {};
        { Afrag FC; buildAt(FC); GEMMF(1, FC, acc1); }
        { Afrag FC; buildAa(FC); GEMMF(2, FC, acc1); }
        { Afrag FC; buildA1(FC); GEMMF(3, FC, acc1); }
        writeTS(acc1, b1S, true);
        __syncthreads();
        {
            Afrag FC; buildAh(FC);
            f32x4 acc2[2] = {};
            GEMMF(4, FC, acc2);
            writeTS(acc2, b2S, false);
        }
        __syncthreads();
    }

    // ---- gate, update, norm, active (am = 1): 16 threads/token, 8 elems each ----
    const int tok = tid >> 4, d0g = (tid & 15) * 8;
    float cv[8];
#pragma unroll
    for (int e = 0; e < 8; ++e) cv[e] = CS[tok][d0g + e];
    float srow[8];
#pragma unroll
    for (int e = 0; e < 8; ++e) srow[e] = h2f(TS[tok][d0g + e]);
    float gp = 0.0f;
#pragma unroll
    for (int e = 0; e < 8; ++e)
        gp += cv[e] * gwS[d0g + e] + srow[e] * gwS[128 + d0g + e];
    gp += __shfl_xor(gp, 1, 16);
    gp += __shfl_xor(gp, 2, 16);
    gp += __shfl_xor(gp, 4, 16);
    gp += __shfl_xor(gp, 8, 16);
    const float gate = 1.0f / (1.0f + __expf(-(gp + gbf)));
    float ss = 0.0f; float up[8];
#pragma unroll
    for (int e = 0; e < 8; ++e) {
        float u = gate * (srow[e] - cv[e]) * 0.1f;
        up[e] = u; ss += u * u;
    }
    ss += __shfl_xor(ss, 1, 16);
    ss += __shfl_xor(ss, 2, 16);
    ss += __shfl_xor(ss, 4, 16);
    ss += __shfl_xor(ss, 8, 16);
    const bool stable = sqrtf(ss) < 0.1f;

    float* op = cur_out + (size_t)(tok0 + tok) * DH + d0g;
    *(float4*)op       = make_float4(cv[0] + up[0], cv[1] + up[1], cv[2] + up[2], cv[3] + up[3]);
    *(float4*)(op + 4) = make_float4(cv[4] + up[4], cv[5] + up[5], cv[6] + up[6], cv[7] + up[7]);
    const int newact = stable ? 0 : 1;
    if ((tid & 15) == 0) {
        active[tok0 + tok] = newact;
        if (newact) atomicAdd(&blkcnt, 1);
    }
    __syncthreads();
    if (tid == 0 && blkcnt > 0) atomicAdd(&counts[1], blkcnt);
}

// ---------------- rounds 1,2: 32 tokens/block, grid 512, dbuf stage (R15 form) ----------------
__global__ __launch_bounds__(256) void round_kernel(
    const float* curr,
    const u32x4* __restrict__ pk, const u16* __restrict__ T0,
    const void* __restrict__ tb, const void* __restrict__ ab,
    const void* __restrict__ b1, const void* __restrict__ b2,
    const void* __restrict__ gw, const void* __restrict__ gb,
    const int* __restrict__ flag, int* active, int* counts, int r,
    float* cur_out, void* dout)
{
    const int isb = *flag;
    const int tok0 = blockIdx.x * 32;
    const int tid = threadIdx.x;
    const bool last = (dout != nullptr);

    if (counts[r] <= 0) {
        if (last) {
            for (int e = tid; e < 32 * DH; e += 256) {
                size_t idx = (size_t)tok0 * DH + e;
                float v = curr[idx];
                if (isb) ((__hip_bfloat16*)dout)[idx] = __float2bfloat16(v);
                else     ((float*)dout)[idx] = v;
            }
        }
        return;
    }

    const int wave = tid >> 6, lane = tid & 63;
    const int qd = lane >> 4, c = lane & 15;
    const int rowg = wave >> 1, colh = wave & 1;

    __shared__ u32x4 WB[2][4][8][64];   // 64 KB double-buffered weight stage
    __shared__ u16 TS[32][132];         // t0 -> h -> synth (f16, 8.4 KB)
    __shared__ float actS[32], tbS[128], abS[128], b1S[128], b2S[128], gwS[256];
    __shared__ int blkcnt;

    auto stageB = [&](int mat, int buf) {
#pragma unroll
        for (int j = 0; j < 8; ++j) {
            const int g = wave * 8 + j, ks = g >> 3, t = g & 7;
            __builtin_amdgcn_global_load_lds(
                (const __attribute__((address_space(1))) u32*)(
                    pk + (((size_t)mat * 4 + ks) * 16 + 2 * t) * 64 + lane),
                (__attribute__((address_space(3))) u32*)&WB[buf][ks][t][0],
                16, 0, 0);
        }
    };
    auto stageF = [&](int mat, int h, int buf) {
#pragma unroll
        for (int j = 0; j < 8; ++j) {
            const int g = wave * 8 + j, kl = g >> 4, p = (g >> 3) & 1, t = g & 7;
            __builtin_amdgcn_global_load_lds(
                (const __attribute__((address_space(1))) u32*)(
                    pk + (((size_t)mat * 4 + 2 * h + kl) * 16 + 2 * t + p) * 64 + lane),
                (__attribute__((address_space(3))) u32*)&WB[buf][kl * 2 + p][t][0],
                16, 0, 0);
        }
    };
    auto gemmB = [&](const Afrag& F, int buf, f32x4 (&acc)[4]) {
#pragma unroll
        for (int ks = 0; ks < 4; ++ks)
#pragma unroll
            for (int tl = 0; tl < 4; ++tl) {
                H8 bh; bh.v = WB[buf][ks][4 * colh + tl][lane];
                acc[tl] = __builtin_amdgcn_mfma_f32_16x16x32_f16(F.l[ks].h, bh.h, acc[tl], 0, 0, 0);
                acc[tl] = __builtin_amdgcn_mfma_f32_16x16x32_f16(F.h[ks].h, bh.h, acc[tl], 0, 0, 0);
            }
    };
    auto gemmFh = [&](const Afrag& F, int h, int buf, f32x4 (&acc)[4]) {
#pragma unroll
        for (int kl = 0; kl < 2; ++kl) {
            const int ks = 2 * h + kl;
#pragma unroll
            for (int tl = 0; tl < 4; ++tl) {
                H8 bh, bl;
                bh.v = WB[buf][kl * 2][4 * colh + tl][lane];
                bl.v = WB[buf][kl * 2 + 1][4 * colh + tl][lane];
                acc[tl] = __builtin_amdgcn_mfma_f32_16x16x32_f16(F.l[ks].h, bh.h, acc[tl], 0, 0, 0);
                acc[tl] = __builtin_amdgcn_mfma_f32_16x16x32_f16(F.h[ks].h, bl.h, acc[tl], 0, 0, 0);
                acc[tl] = __builtin_amdgcn_mfma_f32_16x16x32_f16(F.h[ks].h, bh.h, acc[tl], 0, 0, 0);
            }
        }
    };
    auto STAGE = [&](int mat, int buf) { if (isb) stageB(mat, buf); else stageF(mat, 0, buf); };
    auto GEMM = [&](int mat, const Afrag& F, int buf, f32x4 (&acc)[4]) {
        if (isb) {
            gemmB(F, buf, acc);
        } else {
            gemmFh(F, 0, buf, acc);
            __syncthreads();
            stageF(mat, 1, buf);
            __syncthreads();
            gemmFh(F, 1, buf, acc);
        }
    };

    STAGE(1, 1);   // w1a (t0 comes from cache)
    if (tid < 32) actS[tid] = active[tok0 + tid] ? 1.0f : 0.0f;
    if (tid < 128) {
        tbS[tid] = ldE(tb, tid, isb); abS[tid] = ldE(ab, tid, isb);
        b1S[tid] = ldE(b1, tid, isb); b2S[tid] = ldE(b2, tid, isb);
    }
    gwS[tid] = ldE(gw, tid, isb);
    if (tid == 0) blkcnt = 0;
    const float gbf = ldE(gb, 0, isb);

    const int rowl = 16 * rowg + c;
    const int hr   = 16 * rowg + 4 * qd;

    // load cached t0 into TS (coalesced u32 copy: 32 rows x 64 u32)
    for (int i = tid; i < 32 * 64; i += 256) {
        const int row = i >> 6, c2 = (i & 63) * 2;
        *(u32*)&TS[row][c2] = *(const u32*)&T0[(size_t)(tok0 + row) * DH + c2];
    }
    __syncthreads();                     // buf1 ready, TS(t0) + consts visible

    STAGE(2, 0);                         // w1b
    f32x4 acc1[4] = {};
    const float am_r = actS[rowl];
    {
        float Ac[4][8];
#pragma unroll
        for (int ks = 0; ks < 4; ++ks)
#pragma unroll
            for (int j = 0; j < 8; ++j) {
                const int k = ks * 32 + 8 * qd + j;
                Ac[ks][j] = (h2f(TS[rowl][k]) + tbS[k]) * am_r;   // at
            }
        Afrag FC; splitA(Ac, FC);
        GEMM(1, FC, 1, acc1);
    }
    __syncthreads();                     // buf0 ready, buf1 free

    STAGE(3, 1);                         // w1c
    {
        float Ac[4][8];
#pragma unroll
        for (int ks = 0; ks < 4; ++ks)
#pragma unroll
            for (int j = 0; j < 8; ++j) {
                const int k = ks * 32 + 8 * qd + j;
                Ac[ks][j] = (abS[k] - h2f(TS[rowl][k])) * am_r;   // aa
            }
        Afrag FC; splitA(Ac, FC);
        GEMM(2, FC, 0, acc1);
    }
    __syncthreads();                     // buf1 ready; all TS(t0) reads complete

    STAGE(4, 0);                         // w2
    {
        float Ac[4][8];
        const float* cr = curr + (size_t)(tok0 + rowl) * DH;
#pragma unroll
        for (int ks = 0; ks < 4; ++ks) {
            float4 a0 = *(const float4*)(cr + ks * 32 + 8 * qd);
            float4 a1 = *(const float4*)(cr + ks * 32 + 8 * qd + 4);
            Ac[ks][0] = a0.x * am_r; Ac[ks][1] = a0.y * am_r;
            Ac[ks][2] = a0.z * am_r; Ac[ks][3] = a0.w * am_r;
            Ac[ks][4] = a1.x * am_r; Ac[ks][5] = a1.y * am_r;
            Ac[ks][6] = a1.z * am_r; Ac[ks][7] = a1.w * am_r;
        }
        Afrag FC; splitA(Ac, FC);
        GEMM(3, FC, 1, acc1);
    }
    // h = relu(acc1 + b1) -> TS (t0 dead; own rows/cols only)
#pragma unroll
    for (int tl = 0; tl < 4; ++tl)
#pragma unroll
        for (int rr = 0; rr < 4; ++rr) {
            const int col = 16 * (4 * colh + tl) + c;
            TS[hr + rr][col] = f2h(fmaxf(acc1[tl][rr] + b1S[col], 0.0f));
        }
    __syncthreads();                     // buf0(w2) ready, h visible

    {
        float Ac[4][8];
#pragma unroll
        for (int ks = 0; ks < 4; ++ks)
#pragma unroll
            for (int j = 0; j < 8; ++j)
                Ac[ks][j] = h2f(TS[rowl][ks * 32 + 8 * qd + j]);
        Afrag FC; splitA(Ac, FC);
        f32x4 acc2[4] = {};
        GEMM(4, FC, 0, acc2);
        __syncthreads();                 // all h reads done before synth overwrite
#pragma unroll
        for (int tl = 0; tl < 4; ++tl)
#pragma unroll
            for (int rr = 0; rr < 4; ++rr) {
                const int col = 16 * (4 * colh + tl) + c;
                TS[hr + rr][col] = f2h(acc2[tl][rr] + b2S[col]);
            }
    }
    __syncthreads();                     // synth visible

    // ---- gate, update, norm, active: 8 threads/token, 16 elems each ----
    const int tok = tid >> 3, d0 = (tid & 7) * 16;
    const float am = actS[tok];
    const float* cp = curr + (size_t)(tok0 + tok) * DH + d0;
    float cv[16];
#pragma unroll
    for (int t = 0; t < 4; ++t) {
        float4 vv = *(const float4*)(cp + t * 4);
        cv[t * 4] = vv.x; cv[t * 4 + 1] = vv.y; cv[t * 4 + 2] = vv.z; cv[t * 4 + 3] = vv.w;
    }
    float srow[16];
#pragma unroll
    for (int e = 0; e < 16; ++e) srow[e] = h2f(TS[tok][d0 + e]);
    float gp = 0.0f;
#pragma unroll
    for (int e = 0; e < 16; ++e)
        gp += cv[e] * am * gwS[d0 + e] + srow[e] * gwS[128 + d0 + e];
    gp += __shfl_xor(gp, 1, 8);
    gp += __shfl_xor(gp, 2, 8);
    gp += __shfl_xor(gp, 4, 8);
    const float gate = 1.0f / (1.0f + __expf(-(gp + gbf)));
    float ss = 0.0f; float up[16];
#pragma unroll
    for (int e = 0; e < 16; ++e) {
        float u = gate * (srow[e] - cv[e] * am) * 0.1f;
        up[e] = u; ss += u * u;
    }
    ss += __shfl_xor(ss, 1, 8);
    ss += __shfl_xor(ss, 2, 8);
    ss += __shfl_xor(ss, 4, 8);
    const bool stable = sqrtf(ss) < 0.1f;

    if (last) {
        size_t off = (size_t)(tok0 + tok) * DH + d0;
        if (isb) {
            __hip_bfloat16* op = (__hip_bfloat16*)dout + off;
#pragma unroll
            for (int e = 0; e < 16; ++e) op[e] = __float2bfloat16(cv[e] + up[e]);
        } else {
            float* op = (float*)dout + off;
#pragma unroll
            for (int t = 0; t < 4; ++t)
                *(float4*)(op + t * 4) = make_float4(cv[t * 4] + up[t * 4], cv[t * 4 + 1] + up[t * 4 + 1],
                                                     cv[t * 4 + 2] + up[t * 4 + 2], cv[t * 4 + 3] + up[t * 4 + 3]);
        }
    } else {
        float* op = cur_out + (size_t)(tok0 + tok) * DH + d0;
#pragma unroll
        for (int t = 0; t < 4; ++t)
            *(float4*)(op + t * 4) = make_float4(cv[t * 4] + up[t * 4], cv[t * 4 + 1] + up[t * 4 + 1],
                                                 cv[t * 4 + 2] + up[t * 4 + 2], cv[t * 4 + 3] + up[t * 4 + 3]);
    }
    const int newact = (am > 0.0f && !stable) ? 1 : 0;
    if ((tid & 7) == 0) {
        active[tok0 + tok] = newact;
        if (newact) atomicAdd(&blkcnt, 1);
    }
    __syncthreads();
    if (tid == 0 && blkcnt > 0) atomicAdd(&counts[r + 1], blkcnt);
}

extern "C" void kernel_launch(void* const* d_in, const int* in_sizes, int n_in,
                              void* d_out, int out_size, void* d_ws, size_t ws_size,
                              hipStream_t stream) {
    const void* x  = d_in[0];
    const void* wq = d_in[1];
    const void* wk = d_in[2];
    const void* wv = d_in[3];
    const void* tw = d_in[4];
    const void* tb = d_in[5];
    const void* ab = d_in[6];
    const void* w1 = d_in[7];
    const void* b1 = d_in[8];
    const void* w2 = d_in[9];
    const void* b2 = d_in[10];
    const void* gw = d_in[11];
    const void* gb = d_in[12];

    u32* ws = (u32*)d_ws;
    const size_t N1 = (size_t)BS_ * DH;
    // base layout (~24 MiB): qp | kp | vp | active | counts | flag
    u32* qp = ws;             // Q as u16 (4 MB used of 8 MB region)
    u32* kp = ws + N1;        // K MFMA-frags (4 MB used of 8 MB region)
    u32* vp = ws + 2 * N1;    // V MFMA-frags (4 MB used of 8 MB region)
    int* active = (int*)(ws + 3 * N1);
    int* counts = active + BS_;
    int* flag   = counts + 4;
    float* cur0  = (float*)qp;    // small-ws path only (Q dead after attn)
    float* cur_r = (float*)kp;    // overwrites dead K-frags after attn
    // split-KV x4 extension (f16 partials), ends at 42.2 MB <= 42.3 MB guarantee
    u16* Opart16 = (u16*)(ws + 3 * N1 + 32768);
    u16* lpart16 = (u16*)(ws + 5 * N1 + 32768);
    const bool big_ws = ws_size >= (size_t)42300000;        // constant across calls
    // prepacked QKV W: transient in Opart region (dead before attention writes it)
    u32x4* wpk = (u32x4*)(ws + 3 * N1 + 32768);
    // vp region after attention (V-frags dead): pkRW at base (320 KB), T0 cache at +512 KB (4 MB)
    u32x4* pkRW = (u32x4*)vp;
    u16*   T0c  = (u16*)(vp + 131072);
    u16*   qP    = (u16*)qp;
    u32x4* kfragP = (u32x4*)kp;
    u32x4* vfragP = (u32x4*)vp;

    init_kernel<<<dim3(BS_ / 256), 256, 0, stream>>>(x, flag, active, counts);
    prepack_w_kernel<<<dim3(192), 256, 0, stream>>>(wq, wk, wv, flag, wpk);
    qkv_kernel<<<dim3(BS_ / 64, 1, 3), 256, 0, stream>>>(x, wpk, flag, qP, kfragP, vfragP);
    if (big_ws) {
        attn_split_kernel<<<dim3(S_ / 64, B_, 4), 256, 0, stream>>>(qP, kfragP, vfragP, Opart16, lpart16);
    } else {
        attn_kernel<<<dim3(S_ / 64, B_), 256, 0, stream>>>(qP, kfragP, vfragP, cur0);
    }
    prepack_rw_kernel<<<dim3(40), 256, 0, stream>>>(tw, w1, w2, flag, pkRW);
    // round 0: fused combine + round math + T0 cache
    round0_kernel<<<dim3(BS_ / 16), 256, 0, stream>>>(
        cur0, Opart16, lpart16, pkRW, T0c, tb, ab, b1, b2, gw, gb,
        flag, active, counts, cur_r, big_ws ? 1 : 0);
    round_kernel<<<dim3(BS_ / 32), 256, 0, stream>>>(
        cur_r, pkRW, T0c, tb, ab, b1, b2, gw, gb, flag, active, counts, 1, cur_r, nullptr);
    round_kernel<<<dim3(BS_ / 32), 256, 0, stream>>>(
        cur_r, pkRW, T0c, tb, ab, b1, b2, gw, gb, flag, active, counts, 2, cur_r, d_out);
}